// Round 14
// baseline (588.543 us; speedup 1.0000x reference)
//
#include <hip/hip_runtime.h>
#include <hip/hip_bf16.h>

// ---------------------------------------------------------------------------
// TransformerDecoderBlock (MLA-style) for MI355X / gfx950
// B=2 S=2048 D=2048 NH=16 DH=128 LAT=512
// ---------------------------------------------------------------------------

#define DEVI __device__ __forceinline__

typedef __attribute__((ext_vector_type(8))) short bf16x8;
typedef __attribute__((ext_vector_type(4))) float f32x4;

DEVI unsigned short f2bf(float f) {
  union { float f; unsigned u; } v; v.f = f;
  unsigned r = v.u + 0x7fffu + ((v.u >> 16) & 1u);
  return (unsigned short)(r >> 16);
}

DEVI float bf2f(unsigned short u) {
  union { unsigned u; float f; } v; v.u = ((unsigned)u) << 16;
  return v.f;
}

#define GLDS16(gp, lp)                                              \
  __builtin_amdgcn_global_load_lds(                                 \
      (__attribute__((address_space(1))) void*)(gp),                \
      (__attribute__((address_space(3))) void*)(lp), 16, 0, 0)

#define NEG_INF (-__builtin_inff())

// ---------------------------------------------------------------------------
// cast fp32 -> bf16 (n multiple of 4)
// ---------------------------------------------------------------------------
__global__ __launch_bounds__(256) void cast_f32_bf16(
    const float* __restrict__ in, unsigned short* __restrict__ out, long n) {
  long i = ((long)blockIdx.x * 256 + threadIdx.x) * 4;
  if (i >= n) return;
  const float4 v = *reinterpret_cast<const float4*>(in + i);
  ushort4 o;
  o.x = f2bf(v.x); o.y = f2bf(v.y); o.z = f2bf(v.z); o.w = f2bf(v.w);
  *reinterpret_cast<ushort4*>(out + i) = o;
}

// ---------------------------------------------------------------------------
// weight_prep: one launch for all weight transforms.
//   [0,1024)     W_dq  -> dqkv_t rows 0-511     (transpose)
//   [1024,2048)  W_dkv -> dqkv_t rows 512-1023  (transpose)
//   [2048,3072)  W_uq  -> uq_t                  (transpose)
//   [3072,5120)  W_ukv -> ukv_t                 (transpose)
//   [5120,9216)  W_o   -> wo_b                  (cast)
// ---------------------------------------------------------------------------
__global__ __launch_bounds__(256) void weight_prep(
    const float* __restrict__ W_dq, const float* __restrict__ W_dkv,
    const float* __restrict__ W_uq, const float* __restrict__ W_ukv,
    const float* __restrict__ W_o, unsigned short* __restrict__ dqkv_t,
    unsigned short* __restrict__ uq_t, unsigned short* __restrict__ ukv_t,
    unsigned short* __restrict__ wo_b) {
  __shared__ float tile[32][33];
  const int id = blockIdx.x;
  const int tx = threadIdx.x & 31, ty = threadIdx.x >> 5;  // ty 0..7
  const float* in;
  unsigned short* out;
  int R, C, bx, by;
  if (id < 1024) {
    in = W_dq; out = dqkv_t; R = 2048; C = 512; bx = id & 15; by = id >> 4;
  } else if (id < 2048) {
    const int t = id - 1024;
    in = W_dkv; out = dqkv_t + 512 * 2048; R = 2048; C = 512; bx = t & 15; by = t >> 4;
  } else if (id < 3072) {
    const int t = id - 2048;
    in = W_uq; out = uq_t; R = 512; C = 2048; bx = t & 63; by = t >> 6;
  } else if (id < 5120) {
    const int t = id - 3072;
    in = W_ukv; out = ukv_t; R = 512; C = 4096; bx = t & 127; by = t >> 7;
  } else {
    const long i = ((long)(id - 5120) * 256 + threadIdx.x) * 4;
    const float4 v = *reinterpret_cast<const float4*>(W_o + i);
    ushort4 o;
    o.x = f2bf(v.x); o.y = f2bf(v.y); o.z = f2bf(v.z); o.w = f2bf(v.w);
    *reinterpret_cast<ushort4*>(wo_b + i) = o;
    return;
  }
  const int c0 = bx * 32, r0 = by * 32;
#pragma unroll
  for (int i = 0; i < 32; i += 8)
    tile[ty + i][tx] = in[(long)(r0 + ty + i) * C + c0 + tx];
  __syncthreads();
#pragma unroll
  for (int i = 0; i < 32; i += 8)
    out[(long)(c0 + ty + i) * R + r0 + tx] = f2bf(tile[tx][ty + i]);
}

// ---------------------------------------------------------------------------
// V transpose: KV (B*S x 4096 bf16, V at cols [2048,4096)) ->
//   Vt[bh][d][s]  (32 x 128 x 2048 bf16)
// ---------------------------------------------------------------------------
__global__ __launch_bounds__(256) void v_transpose(
    const unsigned short* __restrict__ KV, unsigned short* __restrict__ Vt) {
  __shared__ unsigned short sh[32][33];
  const int s0 = blockIdx.x * 32, d0 = blockIdx.y * 32, bh = blockIdx.z;
  const int b = bh >> 4, h = bh & 15;
  const int tx = threadIdx.x & 31, ty = threadIdx.x >> 5;  // ty 0..7
#pragma unroll
  for (int i = 0; i < 32; i += 8)
    sh[ty + i][tx] = KV[((long)(b * 2048 + s0 + ty + i)) * 4096 + 2048 + h * 128 + d0 + tx];
  __syncthreads();
#pragma unroll
  for (int i = 0; i < 32; i += 8)
    Vt[((long)(bh * 128 + d0 + ty + i)) * 2048 + s0 + tx] = sh[tx][ty + i];
}

// ---------------------------------------------------------------------------
// block reduce (256 threads = 4 waves)
// ---------------------------------------------------------------------------
DEVI float blockReduceSum(float v) {
  v += __shfl_xor(v, 1);  v += __shfl_xor(v, 2);  v += __shfl_xor(v, 4);
  v += __shfl_xor(v, 8);  v += __shfl_xor(v, 16); v += __shfl_xor(v, 32);
  __shared__ float red[4];
  if ((threadIdx.x & 63) == 0) red[threadIdx.x >> 6] = v;
  __syncthreads();
  v = red[0] + red[1] + red[2] + red[3];
  __syncthreads();
  return v;
}

// ---------------------------------------------------------------------------
// LayerNorm over W cols, one block (256 thr) per row; input row stride ldin.
// ---------------------------------------------------------------------------
template <int W>
__global__ __launch_bounds__(256) void layernorm_bf16(
    const float* __restrict__ in, const float* __restrict__ g,
    const float* __restrict__ b, unsigned short* __restrict__ out, int ldin) {
  constexpr int VPT = W / 256;
  const long row = blockIdx.x;
  const float* x = in + row * ldin;
  float v[VPT];
  float s = 0.f;
#pragma unroll
  for (int i = 0; i < VPT; i++) { v[i] = x[threadIdx.x + i * 256]; s += v[i]; }
  s = blockReduceSum(s);
  const float mean = s * (1.0f / W);
  float s2 = 0.f;
#pragma unroll
  for (int i = 0; i < VPT; i++) { float d = v[i] - mean; s2 += d * d; }
  s2 = blockReduceSum(s2);
  const float rstd = rsqrtf(s2 * (1.0f / W) + 1e-5f);
#pragma unroll
  for (int i = 0; i < VPT; i++) {
    const int c = threadIdx.x + i * 256;
    out[row * W + c] = f2bf((v[i] - mean) * rstd * g[c] + b[c]);
  }
}

// ---------------------------------------------------------------------------
// ln2x512: both 512-wide LayerNorms of one cqkv row in ONE launch, reading
// 4 split-K bf16 partials (p + z*PN) and summing them (no combine pass).
// Threads 0-127 do cq (cols 0-511), 128-255 do ckv (cols 512-1023).
// ---------------------------------------------------------------------------
__global__ __launch_bounds__(256) void ln2x512(
    const unsigned short* __restrict__ part, const float* __restrict__ g1,
    const float* __restrict__ b1, const float* __restrict__ g2,
    const float* __restrict__ b2, unsigned short* __restrict__ cq,
    unsigned short* __restrict__ ckv) {
  constexpr long PN = 4096L * 1024;
  const long row = blockIdx.x;
  const int tid = threadIdx.x;
  const int half = tid >> 7, lt = tid & 127;
  __shared__ float red[8];
  const long off = row * 1024 + half * 512 + lt * 4;
  const ushort4 a0 = *reinterpret_cast<const ushort4*>(part + off);
  const ushort4 a1 = *reinterpret_cast<const ushort4*>(part + PN + off);
  const ushort4 a2 = *reinterpret_cast<const ushort4*>(part + 2 * PN + off);
  const ushort4 a3 = *reinterpret_cast<const ushort4*>(part + 3 * PN + off);
  float4 v;
  v.x = bf2f(a0.x) + bf2f(a1.x) + bf2f(a2.x) + bf2f(a3.x);
  v.y = bf2f(a0.y) + bf2f(a1.y) + bf2f(a2.y) + bf2f(a3.y);
  v.z = bf2f(a0.z) + bf2f(a1.z) + bf2f(a2.z) + bf2f(a3.z);
  v.w = bf2f(a0.w) + bf2f(a1.w) + bf2f(a2.w) + bf2f(a3.w);
  float s = v.x + v.y + v.z + v.w;
  s += __shfl_xor(s, 1);  s += __shfl_xor(s, 2);  s += __shfl_xor(s, 4);
  s += __shfl_xor(s, 8);  s += __shfl_xor(s, 16); s += __shfl_xor(s, 32);
  if ((tid & 63) == 0) red[tid >> 6] = s;
  __syncthreads();
  const float mean = (red[half * 2] + red[half * 2 + 1]) * (1.f / 512.f);
  const float d0 = v.x - mean, d1 = v.y - mean, d2 = v.z - mean, d3 = v.w - mean;
  float s2 = d0 * d0 + d1 * d1 + d2 * d2 + d3 * d3;
  s2 += __shfl_xor(s2, 1);  s2 += __shfl_xor(s2, 2);  s2 += __shfl_xor(s2, 4);
  s2 += __shfl_xor(s2, 8);  s2 += __shfl_xor(s2, 16); s2 += __shfl_xor(s2, 32);
  if ((tid & 63) == 0) red[4 + (tid >> 6)] = s2;
  __syncthreads();
  const float rstd = rsqrtf((red[4 + half * 2] + red[5 + half * 2]) * (1.f / 512.f) + 1e-5f);
  const float* g = half ? g2 : g1;
  const float* b = half ? b2 : b1;
  const float4 gv = *reinterpret_cast<const float4*>(g + lt * 4);
  const float4 bv = *reinterpret_cast<const float4*>(b + lt * 4);
  ushort4 o;
  o.x = f2bf(d0 * rstd * gv.x + bv.x);
  o.y = f2bf(d1 * rstd * gv.y + bv.y);
  o.z = f2bf(d2 * rstd * gv.z + bv.z);
  o.w = f2bf(d3 * rstd * gv.w + bv.w);
  *reinterpret_cast<ushort4*>((half ? ckv : cq) + row * 512 + lt * 4) = o;
}

// ---------------------------------------------------------------------------
// combine_ln: fused W_o-combine (2 split-K partials) + residual + LN (W=2048).
// ---------------------------------------------------------------------------
__global__ __launch_bounds__(256) void combine_ln(
    const unsigned short* __restrict__ p, const float* __restrict__ xres,
    const float* __restrict__ g, const float* __restrict__ b,
    float* __restrict__ x2, unsigned short* __restrict__ h1, long n) {
  const int c0 = threadIdx.x * 8;
  const long base = (long)blockIdx.x * 2048 + c0;
  float v[8];
  float s = 0.f;
#pragma unroll
  for (int hh = 0; hh < 2; hh++) {
    const long i = base + hh * 4;
    const ushort4 a  = *reinterpret_cast<const ushort4*>(p + i);
    const ushort4 bb = *reinterpret_cast<const ushort4*>(p + n + i);
    const float4 r = *reinterpret_cast<const float4*>(xres + i);
    float4 o;
    o.x = r.x + bf2f(a.x) + bf2f(bb.x);
    o.y = r.y + bf2f(a.y) + bf2f(bb.y);
    o.z = r.z + bf2f(a.z) + bf2f(bb.z);
    o.w = r.w + bf2f(a.w) + bf2f(bb.w);
    *reinterpret_cast<float4*>(x2 + i) = o;
    v[hh * 4 + 0] = o.x; v[hh * 4 + 1] = o.y;
    v[hh * 4 + 2] = o.z; v[hh * 4 + 3] = o.w;
    s += o.x + o.y + o.z + o.w;
  }
  s = blockReduceSum(s);
  const float mean = s * (1.0f / 2048.f);
  float s2 = 0.f;
#pragma unroll
  for (int i = 0; i < 8; i++) { float d = v[i] - mean; s2 += d * d; }
  s2 = blockReduceSum(s2);
  const float rstd = rsqrtf(s2 * (1.0f / 2048.f) + 1e-5f);
#pragma unroll
  for (int hh = 0; hh < 2; hh++) {
    const float4 gv = *reinterpret_cast<const float4*>(g + c0 + hh * 4);
    const float4 bv = *reinterpret_cast<const float4*>(b + c0 + hh * 4);
    ushort4 o;
    o.x = f2bf((v[hh * 4 + 0] - mean) * rstd * gv.x + bv.x);
    o.y = f2bf((v[hh * 4 + 1] - mean) * rstd * gv.y + bv.y);
    o.z = f2bf((v[hh * 4 + 2] - mean) * rstd * gv.z + bv.z);
    o.w = f2bf((v[hh * 4 + 3] - mean) * rstd * gv.w + bv.w);
    *reinterpret_cast<ushort4*>(h1 + base + hh * 4) = o;
  }
}

// ---------------------------------------------------------------------------
// gemm_bt: C(MxN) = A * Bt^T, 128x128 tile, BK=32, 4 waves (Q-up GEMM).
// ---------------------------------------------------------------------------
template <bool BIAS, bool RELU, bool RES, bool OBF16>
__global__ __launch_bounds__(256) void gemm_bt(
    const unsigned short* __restrict__ A, const unsigned short* __restrict__ Bt,
    const float* __restrict__ bias, const float* __restrict__ res,
    void* __restrict__ Cout, int M, int N, int K) {
  __shared__ __align__(16) unsigned short As[2][128 * 32];
  __shared__ __align__(16) unsigned short Bs[2][128 * 32];

  const int m0 = blockIdx.x * 128;
  const int n0 = blockIdx.y * 128;
  const int tid = threadIdx.x;
  const int lane = tid & 63, w = tid >> 6;
  const int wr = (w >> 1) * 64, wc = (w & 1) * 64;
  const int lrow = lane & 15, lk = (lane >> 4) * 8;

  f32x4 acc[4][4] = {};

  const int nt = K >> 5;
  const int r_ = (tid * 8) >> 5;      // 0..63
  const int c_ = (tid * 8) & 31;

#define STAGE(buf, t)                                                        \
  {                                                                          \
    const long k0 = (long)(t) * 32;                                          \
    GLDS16(A + (long)(m0 + r_) * K + k0 + c_, &As[buf][tid * 8]);            \
    GLDS16(A + (long)(m0 + 64 + r_) * K + k0 + c_, &As[buf][2048 + tid * 8]);\
    GLDS16(Bt + (long)(n0 + r_) * K + k0 + c_, &Bs[buf][tid * 8]);           \
    GLDS16(Bt + (long)(n0 + 64 + r_) * K + k0 + c_, &Bs[buf][2048 + tid * 8]);\
  }

  STAGE(0, 0)
  __syncthreads();
  int cur = 0;
  for (int t = 0; t < nt; t++) {
    if (t + 1 < nt) STAGE(cur ^ 1, t + 1)
    bf16x8 fa[4], fb[4];
#pragma unroll
    for (int i = 0; i < 4; i++) {
      fa[i] = *reinterpret_cast<const bf16x8*>(&As[cur][(wr + i * 16 + lrow) * 32 + lk]);
      fb[i] = *reinterpret_cast<const bf16x8*>(&Bs[cur][(wc + i * 16 + lrow) * 32 + lk]);
    }
#pragma unroll
    for (int i = 0; i < 4; i++)
#pragma unroll
      for (int j = 0; j < 4; j++)
        acc[i][j] = __builtin_amdgcn_mfma_f32_16x16x32_bf16(fa[i], fb[j], acc[i][j], 0, 0, 0);
    __syncthreads();
    cur ^= 1;
  }
#undef STAGE

#pragma unroll
  for (int i = 0; i < 4; i++) {
#pragma unroll
    for (int j = 0; j < 4; j++) {
      const int row = m0 + wr + i * 16 + ((lane >> 4) << 2);
      const int col = n0 + wc + j * 16 + lrow;
      float bv = 0.f;
      if (BIAS) bv = bias[col];
#pragma unroll
      for (int r = 0; r < 4; r++) {
        float v = acc[i][j][r];
        const long idx = (long)(row + r) * N + col;
        if (BIAS) v += bv;
        if (RELU) v = fmaxf(v, 0.f);
        if (RES) v += res[idx];
        if (OBF16) ((unsigned short*)Cout)[idx] = f2bf(v);
        else       ((float*)Cout)[idx] = v;
      }
    }
  }
}

// ---------------------------------------------------------------------------
// gemm256p: R10-exact 4-phase pipelined 256x256 GEMM, BK=64, 8 waves.
// BEST MEASURED configuration (fc1 ~126 us, MfmaUtil 47.3%, 0 conflicts,
// VGPR 104). Structure plateau — documented failures: BK=32 2-block (R12),
// X/Y reg dbuf (R8 spill), (512,4) bound (R11 spill), 32x32 khi slot (R7
// conflicts). Do not revisit without new counter evidence.
// ---------------------------------------------------------------------------
template <bool BIAS, bool RELU, bool OBF16>
__global__ __launch_bounds__(512, 1) void gemm256p(
    const unsigned short* __restrict__ A, const unsigned short* __restrict__ Bt,
    const float* __restrict__ bias, void* __restrict__ Cout,
    int M, int N, int lda, int ldb, int kLen, long kOff) {
  __shared__ __align__(16) unsigned short L[2][2][2][256 * 32];

  const int m0 = blockIdx.x * 256, n0 = blockIdx.y * 256;
  const long ka = (long)blockIdx.z * kOff;
  const int tid = threadIdx.x;
  const int lane = tid & 63, w = tid >> 6;
  const int sr = (w >> 2) * 64, sc = (w & 3) * 32;
  const int g = lane >> 4, lrow = lane & 15;
  const int r_ = tid >> 2, s_ = tid & 3;

  f32x4 acc[2][2][4][2] = {};
  const int nt = kLen >> 6;

#define STG1(bb, ab, h, kh, t, P, base0, ld)                                   \
  {                                                                            \
    const long k0 = ka + (long)(t) * 64 + (kh) * 32;                           \
    const int rr = (h) * 128 + r_;                                             \
    GLDS16((P) + (long)((base0) + rr) * (ld) + k0 + ((s_ ^ ((rr >> 1) & 3)) << 3), \
           &L[bb][ab][kh][((h) * 512 + tid) * 8]);                             \
  }
#define STG_A(bb, h, t) STG1(bb, 0, h, 0, t, A, m0, lda) STG1(bb, 0, h, 1, t, A, m0, lda)
#define STG_B(bb, h, t) STG1(bb, 1, h, 0, t, Bt, n0, ldb) STG1(bb, 1, h, 1, t, Bt, n0, ldb)

#define RD_A(fa, bu, a)                                                        \
  _Pragma("unroll")                                                            \
  for (int kh = 0; kh < 2; kh++)                                               \
    _Pragma("unroll")                                                          \
    for (int i = 0; i < 4; i++) {                                              \
      const int rr = (a) * 128 + sr + i * 16 + lrow;                           \
      fa[kh][i] = *reinterpret_cast<const bf16x8*>(                            \
          &L[bu][0][kh][(rr * 4 + (g ^ ((rr >> 1) & 3))) * 8]);                \
    }
#define RD_B(fb, bu, b)                                                        \
  _Pragma("unroll")                                                            \
  for (int kh = 0; kh < 2; kh++)                                               \
    _Pragma("unroll")                                                          \
    for (int j = 0; j < 2; j++) {                                              \
      const int rr = (b) * 128 + sc + j * 16 + lrow;                           \
      fb[kh][j] = *reinterpret_cast<const bf16x8*>(                            \
          &L[bu][1][kh][(rr * 4 + (g ^ ((rr >> 1) & 3))) * 8]);                \
    }

#define PH_MFMA(a, b)                                                          \
  __builtin_amdgcn_s_setprio(1);                                               \
  _Pragma("unroll")                                                            \
  for (int kh = 0; kh < 2; kh++)                                               \
    _Pragma("unroll")                                                          \
    for (int i = 0; i < 4; i++)                                                \
      _Pragma("unroll")                                                        \
      for (int j = 0; j < 2; j++)                                              \
        acc[a][b][i][j] = __builtin_amdgcn_mfma_f32_16x16x32_bf16(             \
            fa[kh][i], fb[kh][j], acc[a][b][i][j], 0, 0, 0);                   \
  __builtin_amdgcn_s_setprio(0);

  // prologue: tile 0 -> buf 0, full drain (once per kernel)
  STG_A(0, 0, 0) STG_B(0, 0, 0) STG_B(0, 1, 0) STG_A(0, 1, 0)
  asm volatile("s_waitcnt vmcnt(0)\n\ts_barrier" ::: "memory");

  for (int t = 0; t < nt; t++) {
    const int bu = t & 1, bn = bu ^ 1;
    const bool pf = (t + 1 < nt);
    bf16x8 fa[2][4], fb[2][2];
    // P1 (0,0): fresh fa + fb; stage Ah0(t+1)
    RD_A(fa, bu, 0)
    RD_B(fb, bu, 0)
    if (pf) STG_A(bn, 0, t + 1)
    PH_MFMA(0, 0)
    // P2 (0,1): reuse fa, read Bh1; stage Bh1(t+1)
    RD_B(fb, bu, 1)
    if (pf) STG_B(bn, 1, t + 1)
    PH_MFMA(0, 1)
    if (pf) asm volatile("s_waitcnt vmcnt(4)\n\ts_barrier" ::: "memory");
    else    asm volatile("s_waitcnt vmcnt(0)\n\ts_barrier" ::: "memory");
    // P3 (1,1): reuse fb, read Ah1; stage Bh0(t+1)
    RD_A(fa, bu, 1)
    if (pf) STG_B(bn, 0, t + 1)
    PH_MFMA(1, 1)
    // P4 (1,0): reuse fa, read Bh0; stage Ah1(t+1)
    RD_B(fb, bu, 0)
    if (pf) STG_A(bn, 1, t + 1)
    PH_MFMA(1, 0)
    if (pf) asm volatile("s_waitcnt vmcnt(2)\n\ts_barrier" ::: "memory");
  }
#undef STG1
#undef STG_A
#undef STG_B
#undef RD_A
#undef RD_B
#undef PH_MFMA

  const long zoff = (long)blockIdx.z * (long)M * (long)N;
#pragma unroll
  for (int a = 0; a < 2; a++) {
#pragma unroll
    for (int b = 0; b < 2; b++) {
#pragma unroll
      for (int i = 0; i < 4; i++) {
#pragma unroll
        for (int j = 0; j < 2; j++) {
          const int row = m0 + a * 128 + sr + i * 16 + g * 4;
          const int col = n0 + b * 128 + sc + j * 16 + lrow;
          float bv = 0.f;
          if (BIAS) bv = bias[col];
#pragma unroll
          for (int r = 0; r < 4; r++) {
            float v = acc[a][b][i][j][r];
            if (BIAS) v += bv;
            if (RELU) v = fmaxf(v, 0.f);
            const long idx = zoff + (long)(row + r) * N + col;
            if (OBF16) ((unsigned short*)Cout)[idx] = f2bf(v);
            else       ((float*)Cout)[idx] = v;
          }
        }
      }
    }
  }
}

// ---------------------------------------------------------------------------
// combine split-K partials: out = p0 + p1 [+ bias[col]] + res  (f32)
// ---------------------------------------------------------------------------
template <bool BIAS>
__global__ __launch_bounds__(256) void combine2(
    const unsigned short* __restrict__ p, const float* __restrict__ bias,
    const float* __restrict__ res, float* __restrict__ out, long n) {
  const long i = ((long)blockIdx.x * 256 + threadIdx.x) * 4;
  if (i >= n) return;
  const ushort4 a = *reinterpret_cast<const ushort4*>(p + i);
  const ushort4 b = *reinterpret_cast<const ushort4*>(p + n + i);
  const float4 r = *reinterpret_cast<const float4*>(res + i);
  float4 o;
  o.x = bf2f(a.x) + bf2f(b.x) + r.x;
  o.y = bf2f(a.y) + bf2f(b.y) + r.y;
  o.z = bf2f(a.z) + bf2f(b.z) + r.z;
  o.w = bf2f(a.w) + bf2f(b.w) + r.w;
  if (BIAS) {
    const int col = (int)(i & 2047);
    const float4 bv = *reinterpret_cast<const float4*>(bias + col);
    o.x += bv.x; o.y += bv.y; o.z += bv.z; o.w += bv.w;
  }
  *reinterpret_cast<float4*>(out + i) = o;
}

// ---------------------------------------------------------------------------
// Causal flash attention, KVBLK=64, merged q-tile pair: block handles
// q-tiles A=p (length p+1) and B=31-p (length 32-p) in ONE kv loop of
// 32-p iterations — K/V staged ONCE per kv tile for both (26% less staging
// + barriers than the serial-pair version). Per-tile state in registers.
// ---------------------------------------------------------------------------
__global__ __launch_bounds__(256) void flash_attn(
    const unsigned short* __restrict__ Q, const unsigned short* __restrict__ KV,
    const unsigned short* __restrict__ Vt, unsigned short* __restrict__ O) {
  constexpr int S = 2048;
  const int tid = threadIdx.x, lane = tid & 63, w = tid >> 6;
  const int g = lane >> 4, lcol = lane & 15;
  const int wg = blockIdx.x;              // 0..511
  const int x8 = wg & 7, q64 = wg >> 3;   // q64 0..63
  const int p = q64 & 15, hi = q64 >> 4;
  const int bh = x8 * 4 + hi;             // 0..31
  const int b = bh >> 4, h = bh & 15;
  const long kvrow0 = (long)b * S;
  const int hd0 = h * 128;
  const int tA = p, tB = 31 - p;
  const int qbaseA = tA * 64, qbaseB = tB * 64;

  __shared__ __align__(16) unsigned short Kl[64 * 128];   // [k][d] swizzled
  __shared__ __align__(16) unsigned short Vl[128 * 64];   // [d][k] swizzled
  __shared__ __align__(16) unsigned short Pl[4 * 16 * 72];

  const float kscale = 0.08838834764831845f * 1.4426950408889634f; // /sqrt(128)*log2e

  bf16x8 qfA[4], qfB[4];
#pragma unroll
  for (int dc = 0; dc < 4; dc++) {
    qfA[dc] = *reinterpret_cast<const bf16x8*>(
        Q + (kvrow0 + qbaseA + w * 16 + lcol) * 2048 + hd0 + dc * 32 + g * 8);
    qfB[dc] = *reinterpret_cast<const bf16x8*>(
        Q + (kvrow0 + qbaseB + w * 16 + lcol) * 2048 + hd0 + dc * 32 + g * 8);
  }
  f32x4 oaccA[8] = {}, oaccB[8] = {};
  float mstA[4] = {NEG_INF, NEG_INF, NEG_INF, NEG_INF};
  float mstB[4] = {NEG_INF, NEG_INF, NEG_INF, NEG_INF};
  float lstA[4] = {}, lstB[4] = {};

// process one q-tile against the staged KV tile kt
#define PROC(qf, oacc, mst, lst, qbase, tX)                                    \
  {                                                                            \
    f32x4 sc[4] = {};                                                          \
    __builtin_amdgcn_s_setprio(1);                                             \
    _Pragma("unroll")                                                          \
    for (int dc = 0; dc < 4; dc++) {                                           \
      _Pragma("unroll")                                                        \
      for (int c = 0; c < 4; c++) {                                            \
        const bf16x8 kf = *reinterpret_cast<const bf16x8*>(                    \
            Kl + (c * 16 + lcol) * 128 + 8 * ((4 * dc + g) ^ (lcol & 7)));     \
        sc[c] = __builtin_amdgcn_mfma_f32_16x16x32_bf16(qf[dc], kf, sc[c], 0, 0, 0); \
      }                                                                        \
    }                                                                          \
    __builtin_amdgcn_s_setprio(0);                                             \
    float s[4][4];                                                             \
    const int qrow = (qbase) + w * 16 + g * 4;                                 \
    if (kt == (tX)) {                                                          \
      _Pragma("unroll")                                                        \
      for (int c = 0; c < 4; c++) {                                            \
        const int col = kv0 + c * 16 + lcol;                                   \
        _Pragma("unroll")                                                      \
        for (int r = 0; r < 4; r++)                                            \
          s[c][r] = (col <= qrow + r) ? sc[c][r] * kscale : NEG_INF;           \
      }                                                                        \
    } else {                                                                   \
      _Pragma("unroll")                                                        \
      for (int c = 0; c < 4; c++)                                              \
        _Pragma("unroll")                                                      \
        for (int r = 0; r < 4; r++) s[c][r] = sc[c][r] * kscale;               \
    }                                                                          \
    float pm[4];                                                               \
    _Pragma("unroll")                                                          \
    for (int r = 0; r < 4; r++) {                                              \
      float mx = fmaxf(fmaxf(s[0][r], s[1][r]), fmaxf(s[2][r], s[3][r]));      \
      mx = fmaxf(mx, __shfl_xor(mx, 1));                                       \
      mx = fmaxf(mx, __shfl_xor(mx, 2));                                       \
      mx = fmaxf(mx, __shfl_xor(mx, 4));                                       \
      mx = fmaxf(mx, __shfl_xor(mx, 8));                                       \
      pm[r] = mx;                                                              \
    }                                                                          \
    bool need = false;                                                         \
    _Pragma("unroll")                                                          \
    for (int r = 0; r < 4; r++) need = need || (pm[r] > mst[r] + 11.5f);       \
    if (__any(need)) {                                                         \
      _Pragma("unroll")                                                        \
      for (int r = 0; r < 4; r++) {                                            \
        const float mnew = fmaxf(mst[r], pm[r]);                               \
        const float corr = exp2f(mst[r] - mnew);                               \
        mst[r] = mnew;                                                         \
        lst[r] *= corr;                                                        \
        _Pragma("unroll")                                                      \
        for (int db = 0; db < 8; db++) oacc[db][r] *= corr;                    \
      }                                                                        \
    }                                                                          \
    _Pragma("unroll")                                                          \
    for (int r = 0; r < 4; r++) {                                              \
      float ps = 0.f;                                                          \
      _Pragma("unroll")                                                        \
      for (int c = 0; c < 4; c++) {                                            \
        const float pv = exp2f(s[c][r] - mst[r]);                              \
        Pl[(w * 16 + g * 4 + r) * 72 + c * 16 + lcol] = f2bf(pv);              \
        ps += pv;                                                              \
      }                                                                        \
      ps += __shfl_xor(ps, 1); ps += __shfl_xor(ps, 2);                        \
      ps += __shfl_xor(ps, 4); ps += __shfl_xor(ps, 8);                        \
      lst[r] += ps;                                                            \
    }                                                                          \
    __builtin_amdgcn_s_setprio(1);                                             \
    _Pragma("unroll")                                                          \
    for (int kk = 0; kk < 2; kk++) {                                           \
      const bf16x8 pf = *reinterpret_cast<const bf16x8*>(                      \
          Pl + (w * 16 + lcol) * 72 + kk * 32 + g * 8);                        \
      _Pragma("unroll")                                                        \
      for (int db = 0; db < 8; db++) {                                         \
        const bf16x8 vf = *reinterpret_cast<const bf16x8*>(                    \
            Vl + (db * 16 + lcol) * 64 + 8 * ((4 * kk + g) ^ (lcol & 7)));     \
        oacc[db] = __builtin_amdgcn_mfma_f32_16x16x32_bf16(pf, vf, oacc[db], 0, 0, 0); \
      }                                                                        \
    }                                                                          \
    __builtin_amdgcn_s_setprio(0);                                             \
  }

  const int nk = tB + 1;  // 32 - p
  for (int kt = 0; kt < nk; kt++) {
    const int kv0 = kt * 64;
    __syncthreads();
#pragma unroll
    for (int i = 0; i < 4; i++) {
      const int o16 = i * 256 + tid;
      const int kr = o16 >> 4, ks = o16 & 15;
      GLDS16(KV + (kvrow0 + kv0 + kr) * 4096 + hd0 + 8 * (ks ^ (kr & 7)),
             Kl + o16 * 8);
      const int vd = o16 >> 3, vs = o16 & 7;
      GLDS16(Vt + ((long)bh * 128 + vd) * 2048 + kv0 + 8 * (vs ^ (vd & 7)),
             Vl + o16 * 8);
    }
    __syncthreads();
    PROC(qfB, oaccB, mstB, lstB, qbaseB, tB)
    if (kt <= tA) PROC(qfA, oaccA, mstA, lstA, qbaseA, tA)
  }
#undef PROC

#pragma unroll
  for (int db = 0; db < 8; db++)
#pragma unroll
    for (int r = 0; r < 4; r++) {
      const int qiA = qbaseA + w * 16 + g * 4 + r;
      const int qiB = qbaseB + w * 16 + g * 4 + r;
      O[(kvrow0 + qiA) * 2048 + hd0 + db * 16 + lcol] = f2bf(oaccA[db][r] / lstA[r]);
      O[(kvrow0 + qiB) * 2048 + hd0 + db * 16 + lcol] = f2bf(oaccB[db][r] / lstB[r]);
    }
}

// ---------------------------------------------------------------------------
// launch
// ---------------------------------------------------------------------------
extern "C" void kernel_launch(void* const* d_in, const int* in_sizes, int n_in,
                              void* d_out, int out_size, void* d_ws, size_t ws_size,
                              hipStream_t stream) {
  (void)in_sizes; (void)n_in; (void)out_size; (void)ws_size;
  const float* x     = (const float*)d_in[0];
  const float* W_dq  = (const float*)d_in[1];
  const float* W_uq  = (const float*)d_in[2];
  const float* qlng  = (const float*)d_in[3];
  const float* qlnb  = (const float*)d_in[4];
  const float* W_dkv = (const float*)d_in[5];
  const float* W_ukv = (const float*)d_in[6];
  const float* klng  = (const float*)d_in[7];
  const float* klnb  = (const float*)d_in[8];
  const float* W_o   = (const float*)d_in[9];
  const float* n1g   = (const float*)d_in[10];
  const float* n1b   = (const float*)d_in[11];
  const float* n2g   = (const float*)d_in[12];
  const float* n2b   = (const float*)d_in[13];
  const float* fc1w  = (const float*)d_in[14];
  const float* fc1b  = (const float*)d_in[15];
  const float* fc2w  = (const float*)d_in[16];
  const float* fc2b  = (const float*)d_in[17];
  float* out = (float*)d_out;

  char* ws = (char*)d_ws;
  // region A [0,32M): normed -> Obuf -> fc2bb
  unsigned short* normed = (unsigned short*)(ws + 0);
  unsigned short* Obuf   = (unsigned short*)(ws + 0);
  unsigned short* fc2bb  = (unsigned short*)(ws + 0);
  // region B [32M,64M): cqkv_part (4x8MB bf16) -> KV -> fc1bb -> fc2part
  unsigned short* cqkv_part = (unsigned short*)(ws + 33554432);
  unsigned short* KV        = (unsigned short*)(ws + 33554432);
  unsigned short* fc1bb     = (unsigned short*)(ws + 33554432);
  unsigned short* fc2part   = (unsigned short*)(ws + 33554432);
  // region C [64M,68M): cq
  unsigned short* cq  = (unsigned short*)(ws + 67108864);
  // region D [68M,84.7M): Qb -> h1
  unsigned short* Qb = (unsigned short*)(ws + 71303168);
  unsigned short* h1 = (unsigned short*)(ws + 71303168);
  // region E [84M,117.6M): ckv (early) -> x2 (late)
  unsigned short* ckv = (unsigned short*)(ws + 88080384);
  float* x2           = (float*)(ws + 88080384);
  // region F [116M,180M): Vt -> wopart -> hmid
  unsigned short* Vtb    = (unsigned short*)(ws + 121634816);
  unsigned short* wopart = (unsigned short*)(ws + 121634816);
  unsigned short* hmid   = (unsigned short*)(ws + 121634816);
  // region G [180M,...): transposed/cast weights
  unsigned short* dqkv_t = (unsigned short*)(ws + 188743680);  // 1024 x 2048
  unsigned short* uq_t   = dqkv_t + 2097152;                   // 2048 x 512
  unsigned short* ukv_t  = uq_t + 1048576;                     // 4096 x 512
  unsigned short* wo_b   = ukv_t + 2097152;                    // 2048 x 2048

  const dim3 blk(256);
  const dim3 blk8(512);

  // all weight transposes + W_o cast in one launch
  weight_prep<<<9216, blk, 0, stream>>>(W_dq, W_dkv, W_uq, W_ukv, W_o,
                                        dqkv_t, uq_t, ukv_t, wo_b);

  // LN1
  layernorm_bf16<2048><<<4096, blk, 0, stream>>>(x, n1g, n1b, normed, 2048);
  // cqkv partials = normed @ [W_dq | W_dkv]  (split-K=4, bf16 partials)
  gemm256p<false, false, true><<<dim3(16, 4, 4), blk8, 0, stream>>>(
      normed, dqkv_t, nullptr, cqkv_part, 4096, 1024, 2048, 2048, 512, 512);
  // cq / ckv = LN over summed partials (one launch, no combine pass)
  ln2x512<<<4096, blk, 0, stream>>>(cqkv_part, qlng, qlnb, klng, klnb, cq, ckv);
  // Q = cq @ W_uq
  gemm_bt<false, false, false, true><<<dim3(32, 16), blk, 0, stream>>>(
      cq, uq_t, nullptr, nullptr, Qb, 4096, 2048, 512);
  // KV = ckv @ W_ukv
  gemm256p<false, false, true><<<dim3(16, 16), blk8, 0, stream>>>(
      ckv, ukv_t, nullptr, KV, 4096, 4096, 512, 512, 512, 0);
  // V transpose for conflict-free PV fragments
  v_transpose<<<dim3(64, 4, 32), blk, 0, stream>>>(KV, Vtb);
  // attention (merged q-tile pairs)
  flash_attn<<<dim3(512), blk, 0, stream>>>(Qb, KV, Vtb, Obuf);
  // fc1 weights cast (region B free after attention)
  cast_f32_bf16<<<8192 * 2048 / 1024, blk, 0, stream>>>(fc1w, fc1bb, 8192L * 2048);
  // W_o partials: split-K=2 (Vt dead -> region F)
  gemm256p<false, false, true><<<dim3(16, 8, 2), blk8, 0, stream>>>(
      Obuf, wo_b, nullptr, wopart, 4096, 2048, 2048, 2048, 1024, 1024);
  // fc2 weights cast (region A free after W_o gemm)
  cast_f32_bf16<<<2048 * 8192 / 1024, blk, 0, stream>>>(fc2w, fc2bb, 2048L * 8192);
  // x2 = x + p0 + p1 ; h1 = LN(x2)   (fused)
  combine_ln<<<4096, blk, 0, stream>>>(wopart, x, n2g, n2b, x2, h1, 8388608L);
  // h_mid = relu(h1 @ fc1^T + b1)
  gemm256p<true, true, true><<<dim3(16, 32), blk8, 0, stream>>>(
      h1, fc1bb, fc1b, hmid, 4096, 8192, 2048, 2048, 2048, 0);
  // fc2 partials: split-K=2
  gemm256p<false, false, true><<<dim3(16, 8, 2), blk8, 0, stream>>>(
      hmid, fc2bb, nullptr, fc2part, 4096, 2048, 8192, 8192, 4096, 4096);
  // out = p0 + p1 + b2 + x2
  combine2<true><<<8192, blk, 0, stream>>>(fc2part, fc2b, x2, out, 8388608L);
}

// Round 15
// 536.191 us; speedup vs baseline: 1.0976x; 1.0976x over previous
//
#include <hip/hip_runtime.h>
#include <hip/hip_bf16.h>

// ---------------------------------------------------------------------------
// TransformerDecoderBlock (MLA-style) for MI355X / gfx950
// B=2 S=2048 D=2048 NH=16 DH=128 LAT=512
// ---------------------------------------------------------------------------

#define DEVI __device__ __forceinline__

typedef __attribute__((ext_vector_type(8))) short bf16x8;
typedef __attribute__((ext_vector_type(4))) float f32x4;

DEVI unsigned short f2bf(float f) {
  union { float f; unsigned u; } v; v.f = f;
  unsigned r = v.u + 0x7fffu + ((v.u >> 16) & 1u);
  return (unsigned short)(r >> 16);
}

DEVI float bf2f(unsigned short u) {
  union { unsigned u; float f; } v; v.u = ((unsigned)u) << 16;
  return v.f;
}

#define GLDS16(gp, lp)                                              \
  __builtin_amdgcn_global_load_lds(                                 \
      (__attribute__((address_space(1))) void*)(gp),                \
      (__attribute__((address_space(3))) void*)(lp), 16, 0, 0)

#define NEG_INF (-__builtin_inff())

// ---------------------------------------------------------------------------
// cast fp32 -> bf16 (n multiple of 4)
// ---------------------------------------------------------------------------
__global__ __launch_bounds__(256) void cast_f32_bf16(
    const float* __restrict__ in, unsigned short* __restrict__ out, long n) {
  long i = ((long)blockIdx.x * 256 + threadIdx.x) * 4;
  if (i >= n) return;
  const float4 v = *reinterpret_cast<const float4*>(in + i);
  ushort4 o;
  o.x = f2bf(v.x); o.y = f2bf(v.y); o.z = f2bf(v.z); o.w = f2bf(v.w);
  *reinterpret_cast<ushort4*>(out + i) = o;
}

// ---------------------------------------------------------------------------
// weight_prep: one launch for all weight transforms.
//   [0,1024)     W_dq  -> dqkv_t rows 0-511     (transpose)
//   [1024,2048)  W_dkv -> dqkv_t rows 512-1023  (transpose)
//   [2048,3072)  W_uq  -> uq_t                  (transpose)
//   [3072,5120)  W_ukv -> ukv_t                 (transpose)
//   [5120,9216)  W_o   -> wo_b                  (cast)
// ---------------------------------------------------------------------------
__global__ __launch_bounds__(256) void weight_prep(
    const float* __restrict__ W_dq, const float* __restrict__ W_dkv,
    const float* __restrict__ W_uq, const float* __restrict__ W_ukv,
    const float* __restrict__ W_o, unsigned short* __restrict__ dqkv_t,
    unsigned short* __restrict__ uq_t, unsigned short* __restrict__ ukv_t,
    unsigned short* __restrict__ wo_b) {
  __shared__ float tile[32][33];
  const int id = blockIdx.x;
  const int tx = threadIdx.x & 31, ty = threadIdx.x >> 5;  // ty 0..7
  const float* in;
  unsigned short* out;
  int R, C, bx, by;
  if (id < 1024) {
    in = W_dq; out = dqkv_t; R = 2048; C = 512; bx = id & 15; by = id >> 4;
  } else if (id < 2048) {
    const int t = id - 1024;
    in = W_dkv; out = dqkv_t + 512 * 2048; R = 2048; C = 512; bx = t & 15; by = t >> 4;
  } else if (id < 3072) {
    const int t = id - 2048;
    in = W_uq; out = uq_t; R = 512; C = 2048; bx = t & 63; by = t >> 6;
  } else if (id < 5120) {
    const int t = id - 3072;
    in = W_ukv; out = ukv_t; R = 512; C = 4096; bx = t & 127; by = t >> 7;
  } else {
    const long i = ((long)(id - 5120) * 256 + threadIdx.x) * 4;
    const float4 v = *reinterpret_cast<const float4*>(W_o + i);
    ushort4 o;
    o.x = f2bf(v.x); o.y = f2bf(v.y); o.z = f2bf(v.z); o.w = f2bf(v.w);
    *reinterpret_cast<ushort4*>(wo_b + i) = o;
    return;
  }
  const int c0 = bx * 32, r0 = by * 32;
#pragma unroll
  for (int i = 0; i < 32; i += 8)
    tile[ty + i][tx] = in[(long)(r0 + ty + i) * C + c0 + tx];
  __syncthreads();
#pragma unroll
  for (int i = 0; i < 32; i += 8)
    out[(long)(c0 + ty + i) * R + r0 + tx] = f2bf(tile[tx][ty + i]);
}

// ---------------------------------------------------------------------------
// V transpose: KV (B*S x 4096 bf16, V at cols [2048,4096)) ->
//   Vt[bh][d][s]  (32 x 128 x 2048 bf16)
// ---------------------------------------------------------------------------
__global__ __launch_bounds__(256) void v_transpose(
    const unsigned short* __restrict__ KV, unsigned short* __restrict__ Vt) {
  __shared__ unsigned short sh[32][33];
  const int s0 = blockIdx.x * 32, d0 = blockIdx.y * 32, bh = blockIdx.z;
  const int b = bh >> 4, h = bh & 15;
  const int tx = threadIdx.x & 31, ty = threadIdx.x >> 5;  // ty 0..7
#pragma unroll
  for (int i = 0; i < 32; i += 8)
    sh[ty + i][tx] = KV[((long)(b * 2048 + s0 + ty + i)) * 4096 + 2048 + h * 128 + d0 + tx];
  __syncthreads();
#pragma unroll
  for (int i = 0; i < 32; i += 8)
    Vt[((long)(bh * 128 + d0 + ty + i)) * 2048 + s0 + tx] = sh[tx][ty + i];
}

// ---------------------------------------------------------------------------
// block reduce (256 threads = 4 waves)
// ---------------------------------------------------------------------------
DEVI float blockReduceSum(float v) {
  v += __shfl_xor(v, 1);  v += __shfl_xor(v, 2);  v += __shfl_xor(v, 4);
  v += __shfl_xor(v, 8);  v += __shfl_xor(v, 16); v += __shfl_xor(v, 32);
  __shared__ float red[4];
  if ((threadIdx.x & 63) == 0) red[threadIdx.x >> 6] = v;
  __syncthreads();
  v = red[0] + red[1] + red[2] + red[3];
  __syncthreads();
  return v;
}

// ---------------------------------------------------------------------------
// LayerNorm over W cols, one block (256 thr) per row; input row stride ldin.
// ---------------------------------------------------------------------------
template <int W>
__global__ __launch_bounds__(256) void layernorm_bf16(
    const float* __restrict__ in, const float* __restrict__ g,
    const float* __restrict__ b, unsigned short* __restrict__ out, int ldin) {
  constexpr int VPT = W / 256;
  const long row = blockIdx.x;
  const float* x = in + row * ldin;
  float v[VPT];
  float s = 0.f;
#pragma unroll
  for (int i = 0; i < VPT; i++) { v[i] = x[threadIdx.x + i * 256]; s += v[i]; }
  s = blockReduceSum(s);
  const float mean = s * (1.0f / W);
  float s2 = 0.f;
#pragma unroll
  for (int i = 0; i < VPT; i++) { float d = v[i] - mean; s2 += d * d; }
  s2 = blockReduceSum(s2);
  const float rstd = rsqrtf(s2 * (1.0f / W) + 1e-5f);
#pragma unroll
  for (int i = 0; i < VPT; i++) {
    const int c = threadIdx.x + i * 256;
    out[row * W + c] = f2bf((v[i] - mean) * rstd * g[c] + b[c]);
  }
}

// ---------------------------------------------------------------------------
// ln2x512: both 512-wide LayerNorms of one cqkv row in ONE launch, reading
// 4 split-K bf16 partials (p + z*PN) and summing them (no combine pass).
// Threads 0-127 do cq (cols 0-511), 128-255 do ckv (cols 512-1023).
// ---------------------------------------------------------------------------
__global__ __launch_bounds__(256) void ln2x512(
    const unsigned short* __restrict__ part, const float* __restrict__ g1,
    const float* __restrict__ b1, const float* __restrict__ g2,
    const float* __restrict__ b2, unsigned short* __restrict__ cq,
    unsigned short* __restrict__ ckv) {
  constexpr long PN = 4096L * 1024;
  const long row = blockIdx.x;
  const int tid = threadIdx.x;
  const int half = tid >> 7, lt = tid & 127;
  __shared__ float red[8];
  const long off = row * 1024 + half * 512 + lt * 4;
  const ushort4 a0 = *reinterpret_cast<const ushort4*>(part + off);
  const ushort4 a1 = *reinterpret_cast<const ushort4*>(part + PN + off);
  const ushort4 a2 = *reinterpret_cast<const ushort4*>(part + 2 * PN + off);
  const ushort4 a3 = *reinterpret_cast<const ushort4*>(part + 3 * PN + off);
  float4 v;
  v.x = bf2f(a0.x) + bf2f(a1.x) + bf2f(a2.x) + bf2f(a3.x);
  v.y = bf2f(a0.y) + bf2f(a1.y) + bf2f(a2.y) + bf2f(a3.y);
  v.z = bf2f(a0.z) + bf2f(a1.z) + bf2f(a2.z) + bf2f(a3.z);
  v.w = bf2f(a0.w) + bf2f(a1.w) + bf2f(a2.w) + bf2f(a3.w);
  float s = v.x + v.y + v.z + v.w;
  s += __shfl_xor(s, 1);  s += __shfl_xor(s, 2);  s += __shfl_xor(s, 4);
  s += __shfl_xor(s, 8);  s += __shfl_xor(s, 16); s += __shfl_xor(s, 32);
  if ((tid & 63) == 0) red[tid >> 6] = s;
  __syncthreads();
  const float mean = (red[half * 2] + red[half * 2 + 1]) * (1.f / 512.f);
  const float d0 = v.x - mean, d1 = v.y - mean, d2 = v.z - mean, d3 = v.w - mean;
  float s2 = d0 * d0 + d1 * d1 + d2 * d2 + d3 * d3;
  s2 += __shfl_xor(s2, 1);  s2 += __shfl_xor(s2, 2);  s2 += __shfl_xor(s2, 4);
  s2 += __shfl_xor(s2, 8);  s2 += __shfl_xor(s2, 16); s2 += __shfl_xor(s2, 32);
  if ((tid & 63) == 0) red[4 + (tid >> 6)] = s2;
  __syncthreads();
  const float rstd = rsqrtf((red[4 + half * 2] + red[5 + half * 2]) * (1.f / 512.f) + 1e-5f);
  const float* g = half ? g2 : g1;
  const float* b = half ? b2 : b1;
  const float4 gv = *reinterpret_cast<const float4*>(g + lt * 4);
  const float4 bv = *reinterpret_cast<const float4*>(b + lt * 4);
  ushort4 o;
  o.x = f2bf(d0 * rstd * gv.x + bv.x);
  o.y = f2bf(d1 * rstd * gv.y + bv.y);
  o.z = f2bf(d2 * rstd * gv.z + bv.z);
  o.w = f2bf(d3 * rstd * gv.w + bv.w);
  *reinterpret_cast<ushort4*>((half ? ckv : cq) + row * 512 + lt * 4) = o;
}

// ---------------------------------------------------------------------------
// combine_ln: fused W_o-combine (2 split-K partials) + residual + LN (W=2048).
// ---------------------------------------------------------------------------
__global__ __launch_bounds__(256) void combine_ln(
    const unsigned short* __restrict__ p, const float* __restrict__ xres,
    const float* __restrict__ g, const float* __restrict__ b,
    float* __restrict__ x2, unsigned short* __restrict__ h1, long n) {
  const int c0 = threadIdx.x * 8;
  const long base = (long)blockIdx.x * 2048 + c0;
  float v[8];
  float s = 0.f;
#pragma unroll
  for (int hh = 0; hh < 2; hh++) {
    const long i = base + hh * 4;
    const ushort4 a  = *reinterpret_cast<const ushort4*>(p + i);
    const ushort4 bb = *reinterpret_cast<const ushort4*>(p + n + i);
    const float4 r = *reinterpret_cast<const float4*>(xres + i);
    float4 o;
    o.x = r.x + bf2f(a.x) + bf2f(bb.x);
    o.y = r.y + bf2f(a.y) + bf2f(bb.y);
    o.z = r.z + bf2f(a.z) + bf2f(bb.z);
    o.w = r.w + bf2f(a.w) + bf2f(bb.w);
    *reinterpret_cast<float4*>(x2 + i) = o;
    v[hh * 4 + 0] = o.x; v[hh * 4 + 1] = o.y;
    v[hh * 4 + 2] = o.z; v[hh * 4 + 3] = o.w;
    s += o.x + o.y + o.z + o.w;
  }
  s = blockReduceSum(s);
  const float mean = s * (1.0f / 2048.f);
  float s2 = 0.f;
#pragma unroll
  for (int i = 0; i < 8; i++) { float d = v[i] - mean; s2 += d * d; }
  s2 = blockReduceSum(s2);
  const float rstd = rsqrtf(s2 * (1.0f / 2048.f) + 1e-5f);
#pragma unroll
  for (int hh = 0; hh < 2; hh++) {
    const float4 gv = *reinterpret_cast<const float4*>(g + c0 + hh * 4);
    const float4 bv = *reinterpret_cast<const float4*>(b + c0 + hh * 4);
    ushort4 o;
    o.x = f2bf((v[hh * 4 + 0] - mean) * rstd * gv.x + bv.x);
    o.y = f2bf((v[hh * 4 + 1] - mean) * rstd * gv.y + bv.y);
    o.z = f2bf((v[hh * 4 + 2] - mean) * rstd * gv.z + bv.z);
    o.w = f2bf((v[hh * 4 + 3] - mean) * rstd * gv.w + bv.w);
    *reinterpret_cast<ushort4*>(h1 + base + hh * 4) = o;
  }
}

// ---------------------------------------------------------------------------
// gemm_bt: C(MxN) = A * Bt^T, 128x128 tile, BK=32, 4 waves (Q-up GEMM).
// ---------------------------------------------------------------------------
template <bool BIAS, bool RELU, bool RES, bool OBF16>
__global__ __launch_bounds__(256) void gemm_bt(
    const unsigned short* __restrict__ A, const unsigned short* __restrict__ Bt,
    const float* __restrict__ bias, const float* __restrict__ res,
    void* __restrict__ Cout, int M, int N, int K) {
  __shared__ __align__(16) unsigned short As[2][128 * 32];
  __shared__ __align__(16) unsigned short Bs[2][128 * 32];

  const int m0 = blockIdx.x * 128;
  const int n0 = blockIdx.y * 128;
  const int tid = threadIdx.x;
  const int lane = tid & 63, w = tid >> 6;
  const int wr = (w >> 1) * 64, wc = (w & 1) * 64;
  const int lrow = lane & 15, lk = (lane >> 4) * 8;

  f32x4 acc[4][4] = {};

  const int nt = K >> 5;
  const int r_ = (tid * 8) >> 5;      // 0..63
  const int c_ = (tid * 8) & 31;

#define STAGE(buf, t)                                                        \
  {                                                                          \
    const long k0 = (long)(t) * 32;                                          \
    GLDS16(A + (long)(m0 + r_) * K + k0 + c_, &As[buf][tid * 8]);            \
    GLDS16(A + (long)(m0 + 64 + r_) * K + k0 + c_, &As[buf][2048 + tid * 8]);\
    GLDS16(Bt + (long)(n0 + r_) * K + k0 + c_, &Bs[buf][tid * 8]);           \
    GLDS16(Bt + (long)(n0 + 64 + r_) * K + k0 + c_, &Bs[buf][2048 + tid * 8]);\
  }

  STAGE(0, 0)
  __syncthreads();
  int cur = 0;
  for (int t = 0; t < nt; t++) {
    if (t + 1 < nt) STAGE(cur ^ 1, t + 1)
    bf16x8 fa[4], fb[4];
#pragma unroll
    for (int i = 0; i < 4; i++) {
      fa[i] = *reinterpret_cast<const bf16x8*>(&As[cur][(wr + i * 16 + lrow) * 32 + lk]);
      fb[i] = *reinterpret_cast<const bf16x8*>(&Bs[cur][(wc + i * 16 + lrow) * 32 + lk]);
    }
#pragma unroll
    for (int i = 0; i < 4; i++)
#pragma unroll
      for (int j = 0; j < 4; j++)
        acc[i][j] = __builtin_amdgcn_mfma_f32_16x16x32_bf16(fa[i], fb[j], acc[i][j], 0, 0, 0);
    __syncthreads();
    cur ^= 1;
  }
#undef STAGE

#pragma unroll
  for (int i = 0; i < 4; i++) {
#pragma unroll
    for (int j = 0; j < 4; j++) {
      const int row = m0 + wr + i * 16 + ((lane >> 4) << 2);
      const int col = n0 + wc + j * 16 + lrow;
      float bv = 0.f;
      if (BIAS) bv = bias[col];
#pragma unroll
      for (int r = 0; r < 4; r++) {
        float v = acc[i][j][r];
        const long idx = (long)(row + r) * N + col;
        if (BIAS) v += bv;
        if (RELU) v = fmaxf(v, 0.f);
        if (RES) v += res[idx];
        if (OBF16) ((unsigned short*)Cout)[idx] = f2bf(v);
        else       ((float*)Cout)[idx] = v;
      }
    }
  }
}

// ---------------------------------------------------------------------------
// gemm256p: R10-exact 4-phase pipelined 256x256 GEMM, BK=64, 8 waves.
// BEST MEASURED configuration (fc1 ~126 us, MfmaUtil 47.3%, 0 conflicts,
// VGPR 104). Structure plateau — documented failures: BK=32 2-block (R12),
// X/Y reg dbuf (R8 spill), (512,4) bound (R11 spill), 32x32 khi slot (R7
// conflicts). Do not revisit without new counter evidence.
// ---------------------------------------------------------------------------
template <bool BIAS, bool RELU, bool OBF16>
__global__ __launch_bounds__(512, 1) void gemm256p(
    const unsigned short* __restrict__ A, const unsigned short* __restrict__ Bt,
    const float* __restrict__ bias, void* __restrict__ Cout,
    int M, int N, int lda, int ldb, int kLen, long kOff) {
  __shared__ __align__(16) unsigned short L[2][2][2][256 * 32];

  const int m0 = blockIdx.x * 256, n0 = blockIdx.y * 256;
  const long ka = (long)blockIdx.z * kOff;
  const int tid = threadIdx.x;
  const int lane = tid & 63, w = tid >> 6;
  const int sr = (w >> 2) * 64, sc = (w & 3) * 32;
  const int g = lane >> 4, lrow = lane & 15;
  const int r_ = tid >> 2, s_ = tid & 3;

  f32x4 acc[2][2][4][2] = {};
  const int nt = kLen >> 6;

#define STG1(bb, ab, h, kh, t, P, base0, ld)                                   \
  {                                                                            \
    const long k0 = ka + (long)(t) * 64 + (kh) * 32;                           \
    const int rr = (h) * 128 + r_;                                             \
    GLDS16((P) + (long)((base0) + rr) * (ld) + k0 + ((s_ ^ ((rr >> 1) & 3)) << 3), \
           &L[bb][ab][kh][((h) * 512 + tid) * 8]);                             \
  }
#define STG_A(bb, h, t) STG1(bb, 0, h, 0, t, A, m0, lda) STG1(bb, 0, h, 1, t, A, m0, lda)
#define STG_B(bb, h, t) STG1(bb, 1, h, 0, t, Bt, n0, ldb) STG1(bb, 1, h, 1, t, Bt, n0, ldb)

#define RD_A(fa, bu, a)                                                        \
  _Pragma("unroll")                                                            \
  for (int kh = 0; kh < 2; kh++)                                               \
    _Pragma("unroll")                                                          \
    for (int i = 0; i < 4; i++) {                                              \
      const int rr = (a) * 128 + sr + i * 16 + lrow;                           \
      fa[kh][i] = *reinterpret_cast<const bf16x8*>(                            \
          &L[bu][0][kh][(rr * 4 + (g ^ ((rr >> 1) & 3))) * 8]);                \
    }
#define RD_B(fb, bu, b)                                                        \
  _Pragma("unroll")                                                            \
  for (int kh = 0; kh < 2; kh++)                                               \
    _Pragma("unroll")                                                          \
    for (int j = 0; j < 2; j++) {                                              \
      const int rr = (b) * 128 + sc + j * 16 + lrow;                           \
      fb[kh][j] = *reinterpret_cast<const bf16x8*>(                            \
          &L[bu][1][kh][(rr * 4 + (g ^ ((rr >> 1) & 3))) * 8]);                \
    }

#define PH_MFMA(a, b)                                                          \
  __builtin_amdgcn_s_setprio(1);                                               \
  _Pragma("unroll")                                                            \
  for (int kh = 0; kh < 2; kh++)                                               \
    _Pragma("unroll")                                                          \
    for (int i = 0; i < 4; i++)                                                \
      _Pragma("unroll")                                                        \
      for (int j = 0; j < 2; j++)                                              \
        acc[a][b][i][j] = __builtin_amdgcn_mfma_f32_16x16x32_bf16(             \
            fa[kh][i], fb[kh][j], acc[a][b][i][j], 0, 0, 0);                   \
  __builtin_amdgcn_s_setprio(0);

  // prologue: tile 0 -> buf 0, full drain (once per kernel)
  STG_A(0, 0, 0) STG_B(0, 0, 0) STG_B(0, 1, 0) STG_A(0, 1, 0)
  asm volatile("s_waitcnt vmcnt(0)\n\ts_barrier" ::: "memory");

  for (int t = 0; t < nt; t++) {
    const int bu = t & 1, bn = bu ^ 1;
    const bool pf = (t + 1 < nt);
    bf16x8 fa[2][4], fb[2][2];
    // P1 (0,0): fresh fa + fb; stage Ah0(t+1)
    RD_A(fa, bu, 0)
    RD_B(fb, bu, 0)
    if (pf) STG_A(bn, 0, t + 1)
    PH_MFMA(0, 0)
    // P2 (0,1): reuse fa, read Bh1; stage Bh1(t+1)
    RD_B(fb, bu, 1)
    if (pf) STG_B(bn, 1, t + 1)
    PH_MFMA(0, 1)
    if (pf) asm volatile("s_waitcnt vmcnt(4)\n\ts_barrier" ::: "memory");
    else    asm volatile("s_waitcnt vmcnt(0)\n\ts_barrier" ::: "memory");
    // P3 (1,1): reuse fb, read Ah1; stage Bh0(t+1)
    RD_A(fa, bu, 1)
    if (pf) STG_B(bn, 0, t + 1)
    PH_MFMA(1, 1)
    // P4 (1,0): reuse fa, read Bh0; stage Ah1(t+1)
    RD_B(fb, bu, 0)
    if (pf) STG_A(bn, 1, t + 1)
    PH_MFMA(1, 0)
    if (pf) asm volatile("s_waitcnt vmcnt(2)\n\ts_barrier" ::: "memory");
  }
#undef STG1
#undef STG_A
#undef STG_B
#undef RD_A
#undef RD_B
#undef PH_MFMA

  const long zoff = (long)blockIdx.z * (long)M * (long)N;
#pragma unroll
  for (int a = 0; a < 2; a++) {
#pragma unroll
    for (int b = 0; b < 2; b++) {
#pragma unroll
      for (int i = 0; i < 4; i++) {
#pragma unroll
        for (int j = 0; j < 2; j++) {
          const int row = m0 + a * 128 + sr + i * 16 + g * 4;
          const int col = n0 + b * 128 + sc + j * 16 + lrow;
          float bv = 0.f;
          if (BIAS) bv = bias[col];
#pragma unroll
          for (int r = 0; r < 4; r++) {
            float v = acc[a][b][i][j][r];
            if (BIAS) v += bv;
            if (RELU) v = fmaxf(v, 0.f);
            const long idx = zoff + (long)(row + r) * N + col;
            if (OBF16) ((unsigned short*)Cout)[idx] = f2bf(v);
            else       ((float*)Cout)[idx] = v;
          }
        }
      }
    }
  }
}

// ---------------------------------------------------------------------------
// combine split-K partials: out = p0 + p1 [+ bias[col]] + res  (f32)
// ---------------------------------------------------------------------------
template <bool BIAS>
__global__ __launch_bounds__(256) void combine2(
    const unsigned short* __restrict__ p, const float* __restrict__ bias,
    const float* __restrict__ res, float* __restrict__ out, long n) {
  const long i = ((long)blockIdx.x * 256 + threadIdx.x) * 4;
  if (i >= n) return;
  const ushort4 a = *reinterpret_cast<const ushort4*>(p + i);
  const ushort4 b = *reinterpret_cast<const ushort4*>(p + n + i);
  const float4 r = *reinterpret_cast<const float4*>(res + i);
  float4 o;
  o.x = bf2f(a.x) + bf2f(b.x) + r.x;
  o.y = bf2f(a.y) + bf2f(b.y) + r.y;
  o.z = bf2f(a.z) + bf2f(b.z) + r.z;
  o.w = bf2f(a.w) + bf2f(b.w) + r.w;
  if (BIAS) {
    const int col = (int)(i & 2047);
    const float4 bv = *reinterpret_cast<const float4*>(bias + col);
    o.x += bv.x; o.y += bv.y; o.z += bv.z; o.w += bv.w;
  }
  *reinterpret_cast<float4*>(out + i) = o;
}

// ---------------------------------------------------------------------------
// Causal flash attention, KVBLK=64 (serial q-tile pair, 80 VGPR — the
// measured-best version; R14's merged pair cost 140 VGPR -> occupancy
// 10.8% -> +55 us. Do not merge states without a VGPR budget).
// ---------------------------------------------------------------------------
__global__ __launch_bounds__(256) void flash_attn(
    const unsigned short* __restrict__ Q, const unsigned short* __restrict__ KV,
    const unsigned short* __restrict__ Vt, unsigned short* __restrict__ O) {
  constexpr int S = 2048;
  const int tid = threadIdx.x, lane = tid & 63, w = tid >> 6;
  const int g = lane >> 4, lcol = lane & 15;
  const int wg = blockIdx.x;              // 0..511
  const int x8 = wg & 7, q64 = wg >> 3;   // q64 0..63
  const int p = q64 & 15, hi = q64 >> 4;
  const int bh = x8 * 4 + hi;             // 0..31
  const int b = bh >> 4, h = bh & 15;
  const long kvrow0 = (long)b * S;
  const int hd0 = h * 128;

  __shared__ __align__(16) unsigned short Kl[64 * 128];   // [k][d] swizzled
  __shared__ __align__(16) unsigned short Vl[128 * 64];   // [d][k] swizzled
  __shared__ __align__(16) unsigned short Pl[4 * 16 * 72];

  const float kscale = 0.08838834764831845f * 1.4426950408889634f; // /sqrt(128)*log2e

  for (int ti = 0; ti < 2; ti++) {
    const int t = ti ? (31 - p) : p;
    const int qbase = t * 64;
    bf16x8 qf[4];
#pragma unroll
    for (int dc = 0; dc < 4; dc++)
      qf[dc] = *reinterpret_cast<const bf16x8*>(
          Q + (kvrow0 + qbase + w * 16 + lcol) * 2048 + hd0 + dc * 32 + g * 8);
    f32x4 oacc[8] = {};
    float mst[4] = {NEG_INF, NEG_INF, NEG_INF, NEG_INF};
    float lst[4] = {0.f, 0.f, 0.f, 0.f};
    const int nk = t + 1;
    for (int kt = 0; kt < nk; kt++) {
      const int kv0 = kt * 64;
      __syncthreads();
#pragma unroll
      for (int i = 0; i < 4; i++) {
        const int o16 = i * 256 + tid;
        const int kr = o16 >> 4, ks = o16 & 15;
        GLDS16(KV + (kvrow0 + kv0 + kr) * 4096 + hd0 + 8 * (ks ^ (kr & 7)),
               Kl + o16 * 8);
        const int vd = o16 >> 3, vs = o16 & 7;
        GLDS16(Vt + ((long)bh * 128 + vd) * 2048 + kv0 + 8 * (vs ^ (vd & 7)),
               Vl + o16 * 8);
      }
      __syncthreads();
      // QK^T: 16q x 64k
      f32x4 sc[4] = {};
      __builtin_amdgcn_s_setprio(1);
#pragma unroll
      for (int dc = 0; dc < 4; dc++) {
#pragma unroll
        for (int c = 0; c < 4; c++) {
          const bf16x8 kf = *reinterpret_cast<const bf16x8*>(
              Kl + (c * 16 + lcol) * 128 + 8 * ((4 * dc + g) ^ (lcol & 7)));
          sc[c] = __builtin_amdgcn_mfma_f32_16x16x32_bf16(qf[dc], kf, sc[c], 0, 0, 0);
        }
      }
      __builtin_amdgcn_s_setprio(0);
      float s[4][4];
      const int qrow = qbase + w * 16 + g * 4;
      if (kt == nk - 1) {
#pragma unroll
        for (int c = 0; c < 4; c++) {
          const int col = kv0 + c * 16 + lcol;
#pragma unroll
          for (int r = 0; r < 4; r++)
            s[c][r] = (col <= qrow + r) ? sc[c][r] * kscale : NEG_INF;
        }
      } else {
#pragma unroll
        for (int c = 0; c < 4; c++)
#pragma unroll
          for (int r = 0; r < 4; r++) s[c][r] = sc[c][r] * kscale;
      }
      float pm[4];
#pragma unroll
      for (int r = 0; r < 4; r++) {
        float mx = fmaxf(fmaxf(s[0][r], s[1][r]), fmaxf(s[2][r], s[3][r]));
        mx = fmaxf(mx, __shfl_xor(mx, 1));
        mx = fmaxf(mx, __shfl_xor(mx, 2));
        mx = fmaxf(mx, __shfl_xor(mx, 4));
        mx = fmaxf(mx, __shfl_xor(mx, 8));
        pm[r] = mx;
      }
      bool need = false;
#pragma unroll
      for (int r = 0; r < 4; r++) need = need || (pm[r] > mst[r] + 11.5f);
      if (__any(need)) {
#pragma unroll
        for (int r = 0; r < 4; r++) {
          const float mnew = fmaxf(mst[r], pm[r]);
          const float corr = exp2f(mst[r] - mnew);
          mst[r] = mnew;
          lst[r] *= corr;
#pragma unroll
          for (int db = 0; db < 8; db++) oacc[db][r] *= corr;
        }
      }
#pragma unroll
      for (int r = 0; r < 4; r++) {
        float ps = 0.f;
#pragma unroll
        for (int c = 0; c < 4; c++) {
          const float pv = exp2f(s[c][r] - mst[r]);
          Pl[(w * 16 + g * 4 + r) * 72 + c * 16 + lcol] = f2bf(pv);
          ps += pv;
        }
        ps += __shfl_xor(ps, 1); ps += __shfl_xor(ps, 2);
        ps += __shfl_xor(ps, 4); ps += __shfl_xor(ps, 8);
        lst[r] += ps;
      }
      __builtin_amdgcn_s_setprio(1);
#pragma unroll
      for (int kk = 0; kk < 2; kk++) {
        const bf16x8 pf = *reinterpret_cast<const bf16x8*>(
            Pl + (w * 16 + lcol) * 72 + kk * 32 + g * 8);
#pragma unroll
        for (int db = 0; db < 8; db++) {
          const bf16x8 vf = *reinterpret_cast<const bf16x8*>(
              Vl + (db * 16 + lcol) * 64 + 8 * ((4 * kk + g) ^ (lcol & 7)));
          oacc[db] = __builtin_amdgcn_mfma_f32_16x16x32_bf16(pf, vf, oacc[db], 0, 0, 0);
        }
      }
      __builtin_amdgcn_s_setprio(0);
    }
#pragma unroll
    for (int db = 0; db < 8; db++)
#pragma unroll
      for (int r = 0; r < 4; r++) {
        const int qi = qbase + w * 16 + g * 4 + r;
        O[(kvrow0 + qi) * 2048 + hd0 + db * 16 + lcol] = f2bf(oacc[db][r] / lst[r]);
      }
  }
}

// ---------------------------------------------------------------------------
// launch
// ---------------------------------------------------------------------------
extern "C" void kernel_launch(void* const* d_in, const int* in_sizes, int n_in,
                              void* d_out, int out_size, void* d_ws, size_t ws_size,
                              hipStream_t stream) {
  (void)in_sizes; (void)n_in; (void)out_size; (void)ws_size;
  const float* x     = (const float*)d_in[0];
  const float* W_dq  = (const float*)d_in[1];
  const float* W_uq  = (const float*)d_in[2];
  const float* qlng  = (const float*)d_in[3];
  const float* qlnb  = (const float*)d_in[4];
  const float* W_dkv = (const float*)d_in[5];
  const float* W_ukv = (const float*)d_in[6];
  const float* klng  = (const float*)d_in[7];
  const float* klnb  = (const float*)d_in[8];
  const float* W_o   = (const float*)d_in[9];
  const float* n1g   = (const float*)d_in[10];
  const float* n1b   = (const float*)d_in[11];
  const float* n2g   = (const float*)d_in[12];
  const float* n2b   = (const float*)d_in[13];
  const float* fc1w  = (const float*)d_in[14];
  const float* fc1b  = (const float*)d_in[15];
  const float* fc2w  = (const float*)d_in[16];
  const float* fc2b  = (const float*)d_in[17];
  float* out = (float*)d_out;

  char* ws = (char*)d_ws;
  // region A [0,32M): normed -> Obuf -> fc2bb
  unsigned short* normed = (unsigned short*)(ws + 0);
  unsigned short* Obuf   = (unsigned short*)(ws + 0);
  unsigned short* fc2bb  = (unsigned short*)(ws + 0);
  // region B [32M,64M): cqkv_part (4x8MB bf16) -> KV -> fc1bb -> fc2part
  unsigned short* cqkv_part = (unsigned short*)(ws + 33554432);
  unsigned short* KV        = (unsigned short*)(ws + 33554432);
  unsigned short* fc1bb     = (unsigned short*)(ws + 33554432);
  unsigned short* fc2part   = (unsigned short*)(ws + 33554432);
  // region C [64M,68M): cq
  unsigned short* cq  = (unsigned short*)(ws + 67108864);
  // region D [68M,84.7M): Qb -> h1
  unsigned short* Qb = (unsigned short*)(ws + 71303168);
  unsigned short* h1 = (unsigned short*)(ws + 71303168);
  // region E [84M,117.6M): ckv (early) -> x2 (late)
  unsigned short* ckv = (unsigned short*)(ws + 88080384);
  float* x2           = (float*)(ws + 88080384);
  // region F [116M,180M): Vt -> wopart -> hmid
  unsigned short* Vtb    = (unsigned short*)(ws + 121634816);
  unsigned short* wopart = (unsigned short*)(ws + 121634816);
  unsigned short* hmid   = (unsigned short*)(ws + 121634816);
  // region G [180M,...): transposed/cast weights
  unsigned short* dqkv_t = (unsigned short*)(ws + 188743680);  // 1024 x 2048
  unsigned short* uq_t   = dqkv_t + 2097152;                   // 2048 x 512
  unsigned short* ukv_t  = uq_t + 1048576;                     // 4096 x 512
  unsigned short* wo_b   = ukv_t + 2097152;                    // 2048 x 2048

  const dim3 blk(256);
  const dim3 blk8(512);

  // all weight transposes + W_o cast in one launch
  weight_prep<<<9216, blk, 0, stream>>>(W_dq, W_dkv, W_uq, W_ukv, W_o,
                                        dqkv_t, uq_t, ukv_t, wo_b);

  // LN1
  layernorm_bf16<2048><<<4096, blk, 0, stream>>>(x, n1g, n1b, normed, 2048);
  // cqkv partials = normed @ [W_dq | W_dkv]  (split-K=4, bf16 partials)
  gemm256p<false, false, true><<<dim3(16, 4, 4), blk8, 0, stream>>>(
      normed, dqkv_t, nullptr, cqkv_part, 4096, 1024, 2048, 2048, 512, 512);
  // cq / ckv = LN over summed partials (one launch, no combine pass)
  ln2x512<<<4096, blk, 0, stream>>>(cqkv_part, qlng, qlnb, klng, klnb, cq, ckv);
  // Q = cq @ W_uq
  gemm_bt<false, false, false, true><<<dim3(32, 16), blk, 0, stream>>>(
      cq, uq_t, nullptr, nullptr, Qb, 4096, 2048, 512);
  // KV = ckv @ W_ukv
  gemm256p<false, false, true><<<dim3(16, 16), blk8, 0, stream>>>(
      ckv, ukv_t, nullptr, KV, 4096, 4096, 512, 512, 512, 0);
  // V transpose for conflict-free PV fragments
  v_transpose<<<dim3(64, 4, 32), blk, 0, stream>>>(KV, Vtb);
  // attention (serial q-tile pairs, 80-VGPR version)
  flash_attn<<<dim3(512), blk, 0, stream>>>(Qb, KV, Vtb, Obuf);
  // fc1 weights cast (region B free after attention)
  cast_f32_bf16<<<8192 * 2048 / 1024, blk, 0, stream>>>(fc1w, fc1bb, 8192L * 2048);
  // W_o partials: split-K=2 (Vt dead -> region F)
  gemm256p<false, false, true><<<dim3(16, 8, 2), blk8, 0, stream>>>(
      Obuf, wo_b, nullptr, wopart, 4096, 2048, 2048, 2048, 1024, 1024);
  // fc2 weights cast (region A free after W_o gemm)
  cast_f32_bf16<<<2048 * 8192 / 1024, blk, 0, stream>>>(fc2w, fc2bb, 2048L * 8192);
  // x2 = x + p0 + p1 ; h1 = LN(x2)   (fused)
  combine_ln<<<4096, blk, 0, stream>>>(wopart, x, n2g, n2b, x2, h1, 8388608L);
  // h_mid = relu(h1 @ fc1^T + b1)
  gemm256p<true, true, true><<<dim3(16, 32), blk8, 0, stream>>>(
      h1, fc1bb, fc1b, hmid, 4096, 8192, 2048, 2048, 2048, 0);
  // fc2 partials: split-K=2
  gemm256p<false, false, true><<<dim3(16, 8, 2), blk8, 0, stream>>>(
      hmid, fc2bb, nullptr, fc2part, 4096, 2048, 8192, 8192, 4096, 4096);
  // out = p0 + p1 + b2 + x2
  combine2<true><<<8192, blk, 0, stream>>>(fc2part, fc2b, x2, out, 8388608L);
}

// Round 16
// 523.974 us; speedup vs baseline: 1.1232x; 1.0233x over previous
//
#include <hip/hip_runtime.h>
#include <hip/hip_bf16.h>

// ---------------------------------------------------------------------------
// TransformerDecoderBlock (MLA-style) for MI355X / gfx950
// B=2 S=2048 D=2048 NH=16 DH=128 LAT=512
// ---------------------------------------------------------------------------

#define DEVI __device__ __forceinline__

typedef __attribute__((ext_vector_type(8))) short bf16x8;
typedef __attribute__((ext_vector_type(4))) float f32x4;

DEVI unsigned short f2bf(float f) {
  union { float f; unsigned u; } v; v.f = f;
  unsigned r = v.u + 0x7fffu + ((v.u >> 16) & 1u);
  return (unsigned short)(r >> 16);
}

DEVI float bf2f(unsigned short u) {
  union { unsigned u; float f; } v; v.u = ((unsigned)u) << 16;
  return v.f;
}

#define GLDS16(gp, lp)                                              \
  __builtin_amdgcn_global_load_lds(                                 \
      (__attribute__((address_space(1))) void*)(gp),                \
      (__attribute__((address_space(3))) void*)(lp), 16, 0, 0)

#define NEG_INF (-__builtin_inff())

// ---------------------------------------------------------------------------
// cast2: fc1 (n1 elems) then fc2 weights in one launch; block-uniform split.
// ---------------------------------------------------------------------------
__global__ __launch_bounds__(256) void cast2_f32_bf16(
    const float* __restrict__ in1, unsigned short* __restrict__ out1, long n1,
    const float* __restrict__ in2, unsigned short* __restrict__ out2) {
  long i = ((long)blockIdx.x * 256 + threadIdx.x) * 4;
  const float* in = in1;
  unsigned short* out = out1;
  if (i >= n1) { i -= n1; in = in2; out = out2; }
  const float4 v = *reinterpret_cast<const float4*>(in + i);
  ushort4 o;
  o.x = f2bf(v.x); o.y = f2bf(v.y); o.z = f2bf(v.z); o.w = f2bf(v.w);
  *reinterpret_cast<ushort4*>(out + i) = o;
}

// ---------------------------------------------------------------------------
// weight_prep: one launch for all weight transforms.
//   [0,1024)     W_dq  -> dqkv_t rows 0-511     (transpose)
//   [1024,2048)  W_dkv -> dqkv_t rows 512-1023  (transpose)
//   [2048,3072)  W_uq  -> uq_t                  (transpose)
//   [3072,5120)  W_ukv -> ukv_t                 (transpose)
//   [5120,9216)  W_o   -> wo_b                  (cast)
// ---------------------------------------------------------------------------
__global__ __launch_bounds__(256) void weight_prep(
    const float* __restrict__ W_dq, const float* __restrict__ W_dkv,
    const float* __restrict__ W_uq, const float* __restrict__ W_ukv,
    const float* __restrict__ W_o, unsigned short* __restrict__ dqkv_t,
    unsigned short* __restrict__ uq_t, unsigned short* __restrict__ ukv_t,
    unsigned short* __restrict__ wo_b) {
  __shared__ float tile[32][33];
  const int id = blockIdx.x;
  const int tx = threadIdx.x & 31, ty = threadIdx.x >> 5;  // ty 0..7
  const float* in;
  unsigned short* out;
  int R, C, bx, by;
  if (id < 1024) {
    in = W_dq; out = dqkv_t; R = 2048; C = 512; bx = id & 15; by = id >> 4;
  } else if (id < 2048) {
    const int t = id - 1024;
    in = W_dkv; out = dqkv_t + 512 * 2048; R = 2048; C = 512; bx = t & 15; by = t >> 4;
  } else if (id < 3072) {
    const int t = id - 2048;
    in = W_uq; out = uq_t; R = 512; C = 2048; bx = t & 63; by = t >> 6;
  } else if (id < 5120) {
    const int t = id - 3072;
    in = W_ukv; out = ukv_t; R = 512; C = 4096; bx = t & 127; by = t >> 7;
  } else {
    const long i = ((long)(id - 5120) * 256 + threadIdx.x) * 4;
    const float4 v = *reinterpret_cast<const float4*>(W_o + i);
    ushort4 o;
    o.x = f2bf(v.x); o.y = f2bf(v.y); o.z = f2bf(v.z); o.w = f2bf(v.w);
    *reinterpret_cast<ushort4*>(wo_b + i) = o;
    return;
  }
  const int c0 = bx * 32, r0 = by * 32;
#pragma unroll
  for (int i = 0; i < 32; i += 8)
    tile[ty + i][tx] = in[(long)(r0 + ty + i) * C + c0 + tx];
  __syncthreads();
#pragma unroll
  for (int i = 0; i < 32; i += 8)
    out[(long)(c0 + ty + i) * R + r0 + tx] = f2bf(tile[tx][ty + i]);
}

// ---------------------------------------------------------------------------
// block reduce (256 threads = 4 waves)
// ---------------------------------------------------------------------------
DEVI float blockReduceSum(float v) {
  v += __shfl_xor(v, 1);  v += __shfl_xor(v, 2);  v += __shfl_xor(v, 4);
  v += __shfl_xor(v, 8);  v += __shfl_xor(v, 16); v += __shfl_xor(v, 32);
  __shared__ float red[4];
  if ((threadIdx.x & 63) == 0) red[threadIdx.x >> 6] = v;
  __syncthreads();
  v = red[0] + red[1] + red[2] + red[3];
  __syncthreads();
  return v;
}

// ---------------------------------------------------------------------------
// LayerNorm over W cols, one block (256 thr) per row; input row stride ldin.
// ---------------------------------------------------------------------------
template <int W>
__global__ __launch_bounds__(256) void layernorm_bf16(
    const float* __restrict__ in, const float* __restrict__ g,
    const float* __restrict__ b, unsigned short* __restrict__ out, int ldin) {
  constexpr int VPT = W / 256;
  const long row = blockIdx.x;
  const float* x = in + row * ldin;
  float v[VPT];
  float s = 0.f;
#pragma unroll
  for (int i = 0; i < VPT; i++) { v[i] = x[threadIdx.x + i * 256]; s += v[i]; }
  s = blockReduceSum(s);
  const float mean = s * (1.0f / W);
  float s2 = 0.f;
#pragma unroll
  for (int i = 0; i < VPT; i++) { float d = v[i] - mean; s2 += d * d; }
  s2 = blockReduceSum(s2);
  const float rstd = rsqrtf(s2 * (1.0f / W) + 1e-5f);
#pragma unroll
  for (int i = 0; i < VPT; i++) {
    const int c = threadIdx.x + i * 256;
    out[row * W + c] = f2bf((v[i] - mean) * rstd * g[c] + b[c]);
  }
}

// ---------------------------------------------------------------------------
// ln2x512: both 512-wide LayerNorms of one cqkv row in ONE launch, reading
// 4 split-K bf16 partials (p + z*PN) and summing them (no combine pass).
// ---------------------------------------------------------------------------
__global__ __launch_bounds__(256) void ln2x512(
    const unsigned short* __restrict__ part, const float* __restrict__ g1,
    const float* __restrict__ b1, const float* __restrict__ g2,
    const float* __restrict__ b2, unsigned short* __restrict__ cq,
    unsigned short* __restrict__ ckv) {
  constexpr long PN = 4096L * 1024;
  const long row = blockIdx.x;
  const int tid = threadIdx.x;
  const int half = tid >> 7, lt = tid & 127;
  __shared__ float red[8];
  const long off = row * 1024 + half * 512 + lt * 4;
  const ushort4 a0 = *reinterpret_cast<const ushort4*>(part + off);
  const ushort4 a1 = *reinterpret_cast<const ushort4*>(part + PN + off);
  const ushort4 a2 = *reinterpret_cast<const ushort4*>(part + 2 * PN + off);
  const ushort4 a3 = *reinterpret_cast<const ushort4*>(part + 3 * PN + off);
  float4 v;
  v.x = bf2f(a0.x) + bf2f(a1.x) + bf2f(a2.x) + bf2f(a3.x);
  v.y = bf2f(a0.y) + bf2f(a1.y) + bf2f(a2.y) + bf2f(a3.y);
  v.z = bf2f(a0.z) + bf2f(a1.z) + bf2f(a2.z) + bf2f(a3.z);
  v.w = bf2f(a0.w) + bf2f(a1.w) + bf2f(a2.w) + bf2f(a3.w);
  float s = v.x + v.y + v.z + v.w;
  s += __shfl_xor(s, 1);  s += __shfl_xor(s, 2);  s += __shfl_xor(s, 4);
  s += __shfl_xor(s, 8);  s += __shfl_xor(s, 16); s += __shfl_xor(s, 32);
  if ((tid & 63) == 0) red[tid >> 6] = s;
  __syncthreads();
  const float mean = (red[half * 2] + red[half * 2 + 1]) * (1.f / 512.f);
  const float d0 = v.x - mean, d1 = v.y - mean, d2 = v.z - mean, d3 = v.w - mean;
  float s2 = d0 * d0 + d1 * d1 + d2 * d2 + d3 * d3;
  s2 += __shfl_xor(s2, 1);  s2 += __shfl_xor(s2, 2);  s2 += __shfl_xor(s2, 4);
  s2 += __shfl_xor(s2, 8);  s2 += __shfl_xor(s2, 16); s2 += __shfl_xor(s2, 32);
  if ((tid & 63) == 0) red[4 + (tid >> 6)] = s2;
  __syncthreads();
  const float rstd = rsqrtf((red[4 + half * 2] + red[5 + half * 2]) * (1.f / 512.f) + 1e-5f);
  const float* g = half ? g2 : g1;
  const float* b = half ? b2 : b1;
  const float4 gv = *reinterpret_cast<const float4*>(g + lt * 4);
  const float4 bv = *reinterpret_cast<const float4*>(b + lt * 4);
  ushort4 o;
  o.x = f2bf(d0 * rstd * gv.x + bv.x);
  o.y = f2bf(d1 * rstd * gv.y + bv.y);
  o.z = f2bf(d2 * rstd * gv.z + bv.z);
  o.w = f2bf(d3 * rstd * gv.w + bv.w);
  *reinterpret_cast<ushort4*>((half ? ckv : cq) + row * 512 + lt * 4) = o;
}

// ---------------------------------------------------------------------------
// combine_ln: fused W_o-combine (2 split-K partials) + residual + LN (W=2048).
// ---------------------------------------------------------------------------
__global__ __launch_bounds__(256) void combine_ln(
    const unsigned short* __restrict__ p, const float* __restrict__ xres,
    const float* __restrict__ g, const float* __restrict__ b,
    float* __restrict__ x2, unsigned short* __restrict__ h1, long n) {
  const int c0 = threadIdx.x * 8;
  const long base = (long)blockIdx.x * 2048 + c0;
  float v[8];
  float s = 0.f;
#pragma unroll
  for (int hh = 0; hh < 2; hh++) {
    const long i = base + hh * 4;
    const ushort4 a  = *reinterpret_cast<const ushort4*>(p + i);
    const ushort4 bb = *reinterpret_cast<const ushort4*>(p + n + i);
    const float4 r = *reinterpret_cast<const float4*>(xres + i);
    float4 o;
    o.x = r.x + bf2f(a.x) + bf2f(bb.x);
    o.y = r.y + bf2f(a.y) + bf2f(bb.y);
    o.z = r.z + bf2f(a.z) + bf2f(bb.z);
    o.w = r.w + bf2f(a.w) + bf2f(bb.w);
    *reinterpret_cast<float4*>(x2 + i) = o;
    v[hh * 4 + 0] = o.x; v[hh * 4 + 1] = o.y;
    v[hh * 4 + 2] = o.z; v[hh * 4 + 3] = o.w;
    s += o.x + o.y + o.z + o.w;
  }
  s = blockReduceSum(s);
  const float mean = s * (1.0f / 2048.f);
  float s2 = 0.f;
#pragma unroll
  for (int i = 0; i < 8; i++) { float d = v[i] - mean; s2 += d * d; }
  s2 = blockReduceSum(s2);
  const float rstd = rsqrtf(s2 * (1.0f / 2048.f) + 1e-5f);
#pragma unroll
  for (int hh = 0; hh < 2; hh++) {
    const float4 gv = *reinterpret_cast<const float4*>(g + c0 + hh * 4);
    const float4 bv = *reinterpret_cast<const float4*>(b + c0 + hh * 4);
    ushort4 o;
    o.x = f2bf((v[hh * 4 + 0] - mean) * rstd * gv.x + bv.x);
    o.y = f2bf((v[hh * 4 + 1] - mean) * rstd * gv.y + bv.y);
    o.z = f2bf((v[hh * 4 + 2] - mean) * rstd * gv.z + bv.z);
    o.w = f2bf((v[hh * 4 + 3] - mean) * rstd * gv.w + bv.w);
    *reinterpret_cast<ushort4*>(h1 + base + hh * 4) = o;
  }
}

// ---------------------------------------------------------------------------
// gemm_bt: C(MxN) = A * Bt^T, 128x128 tile, BK=32, 4 waves (Q-up GEMM).
// ---------------------------------------------------------------------------
template <bool BIAS, bool RELU, bool RES, bool OBF16>
__global__ __launch_bounds__(256) void gemm_bt(
    const unsigned short* __restrict__ A, const unsigned short* __restrict__ Bt,
    const float* __restrict__ bias, const float* __restrict__ res,
    void* __restrict__ Cout, int M, int N, int K) {
  __shared__ __align__(16) unsigned short As[2][128 * 32];
  __shared__ __align__(16) unsigned short Bs[2][128 * 32];

  const int m0 = blockIdx.x * 128;
  const int n0 = blockIdx.y * 128;
  const int tid = threadIdx.x;
  const int lane = tid & 63, w = tid >> 6;
  const int wr = (w >> 1) * 64, wc = (w & 1) * 64;
  const int lrow = lane & 15, lk = (lane >> 4) * 8;

  f32x4 acc[4][4] = {};

  const int nt = K >> 5;
  const int r_ = (tid * 8) >> 5;      // 0..63
  const int c_ = (tid * 8) & 31;

#define STAGE(buf, t)                                                        \
  {                                                                          \
    const long k0 = (long)(t) * 32;                                          \
    GLDS16(A + (long)(m0 + r_) * K + k0 + c_, &As[buf][tid * 8]);            \
    GLDS16(A + (long)(m0 + 64 + r_) * K + k0 + c_, &As[buf][2048 + tid * 8]);\
    GLDS16(Bt + (long)(n0 + r_) * K + k0 + c_, &Bs[buf][tid * 8]);           \
    GLDS16(Bt + (long)(n0 + 64 + r_) * K + k0 + c_, &Bs[buf][2048 + tid * 8]);\
  }

  STAGE(0, 0)
  __syncthreads();
  int cur = 0;
  for (int t = 0; t < nt; t++) {
    if (t + 1 < nt) STAGE(cur ^ 1, t + 1)
    bf16x8 fa[4], fb[4];
#pragma unroll
    for (int i = 0; i < 4; i++) {
      fa[i] = *reinterpret_cast<const bf16x8*>(&As[cur][(wr + i * 16 + lrow) * 32 + lk]);
      fb[i] = *reinterpret_cast<const bf16x8*>(&Bs[cur][(wc + i * 16 + lrow) * 32 + lk]);
    }
#pragma unroll
    for (int i = 0; i < 4; i++)
#pragma unroll
      for (int j = 0; j < 4; j++)
        acc[i][j] = __builtin_amdgcn_mfma_f32_16x16x32_bf16(fa[i], fb[j], acc[i][j], 0, 0, 0);
    __syncthreads();
    cur ^= 1;
  }
#undef STAGE

#pragma unroll
  for (int i = 0; i < 4; i++) {
#pragma unroll
    for (int j = 0; j < 4; j++) {
      const int row = m0 + wr + i * 16 + ((lane >> 4) << 2);
      const int col = n0 + wc + j * 16 + lrow;
      float bv = 0.f;
      if (BIAS) bv = bias[col];
#pragma unroll
      for (int r = 0; r < 4; r++) {
        float v = acc[i][j][r];
        const long idx = (long)(row + r) * N + col;
        if (BIAS) v += bv;
        if (RELU) v = fmaxf(v, 0.f);
        if (RES) v += res[idx];
        if (OBF16) ((unsigned short*)Cout)[idx] = f2bf(v);
        else       ((float*)Cout)[idx] = v;
      }
    }
  }
}

// ---------------------------------------------------------------------------
// gemm256p: R10-exact 4-phase pipelined 256x256 GEMM, BK=64, 8 waves.
// BEST MEASURED configuration (fc1 ~126 us, MfmaUtil 47.3%, 0 conflicts,
// VGPR 104). Structure plateau — documented failures: BK=32 2-block (R12),
// X/Y reg dbuf (R8 spill), (512,4) bound (R11 spill), 32x32 khi slot (R7
// conflicts). Do not revisit without new counter evidence.
// NEW: VT template flag — for blocks with n0 >= 2048 (KV GEMM V-half,
// block-uniform) the epilogue writes DIRECTLY into Vt[bh][d][s] (8B
// ushort4 stores, contiguous in s) and skips the normal C write. This
// fuses v_transpose into the GEMM (flash only reads K cols <2048 from KV).
// ---------------------------------------------------------------------------
template <bool BIAS, bool RELU, bool OBF16, bool VT>
__global__ __launch_bounds__(512, 1) void gemm256p(
    const unsigned short* __restrict__ A, const unsigned short* __restrict__ Bt,
    const float* __restrict__ bias, void* __restrict__ Cout,
    unsigned short* __restrict__ VtOut,
    int M, int N, int lda, int ldb, int kLen, long kOff) {
  __shared__ __align__(16) unsigned short L[2][2][2][256 * 32];

  const int m0 = blockIdx.x * 256, n0 = blockIdx.y * 256;
  const long ka = (long)blockIdx.z * kOff;
  const int tid = threadIdx.x;
  const int lane = tid & 63, w = tid >> 6;
  const int sr = (w >> 2) * 64, sc = (w & 3) * 32;
  const int g = lane >> 4, lrow = lane & 15;
  const int r_ = tid >> 2, s_ = tid & 3;

  f32x4 acc[2][2][4][2] = {};
  const int nt = kLen >> 6;

#define STG1(bb, ab, h, kh, t, P, base0, ld)                                   \
  {                                                                            \
    const long k0 = ka + (long)(t) * 64 + (kh) * 32;                           \
    const int rr = (h) * 128 + r_;                                             \
    GLDS16((P) + (long)((base0) + rr) * (ld) + k0 + ((s_ ^ ((rr >> 1) & 3)) << 3), \
           &L[bb][ab][kh][((h) * 512 + tid) * 8]);                             \
  }
#define STG_A(bb, h, t) STG1(bb, 0, h, 0, t, A, m0, lda) STG1(bb, 0, h, 1, t, A, m0, lda)
#define STG_B(bb, h, t) STG1(bb, 1, h, 0, t, Bt, n0, ldb) STG1(bb, 1, h, 1, t, Bt, n0, ldb)

#define RD_A(fa, bu, a)                                                        \
  _Pragma("unroll")                                                            \
  for (int kh = 0; kh < 2; kh++)                                               \
    _Pragma("unroll")                                                          \
    for (int i = 0; i < 4; i++) {                                              \
      const int rr = (a) * 128 + sr + i * 16 + lrow;                           \
      fa[kh][i] = *reinterpret_cast<const bf16x8*>(                            \
          &L[bu][0][kh][(rr * 4 + (g ^ ((rr >> 1) & 3))) * 8]);                \
    }
#define RD_B(fb, bu, b)                                                        \
  _Pragma("unroll")                                                            \
  for (int kh = 0; kh < 2; kh++)                                               \
    _Pragma("unroll")                                                          \
    for (int j = 0; j < 2; j++) {                                              \
      const int rr = (b) * 128 + sc + j * 16 + lrow;                           \
      fb[kh][j] = *reinterpret_cast<const bf16x8*>(                            \
          &L[bu][1][kh][(rr * 4 + (g ^ ((rr >> 1) & 3))) * 8]);                \
    }

#define PH_MFMA(a, b)                                                          \
  __builtin_amdgcn_s_setprio(1);                                               \
  _Pragma("unroll")                                                            \
  for (int kh = 0; kh < 2; kh++)                                               \
    _Pragma("unroll")                                                          \
    for (int i = 0; i < 4; i++)                                                \
      _Pragma("unroll")                                                        \
      for (int j = 0; j < 2; j++)                                              \
        acc[a][b][i][j] = __builtin_amdgcn_mfma_f32_16x16x32_bf16(             \
            fa[kh][i], fb[kh][j], acc[a][b][i][j], 0, 0, 0);                   \
  __builtin_amdgcn_s_setprio(0);

  // prologue: tile 0 -> buf 0, full drain (once per kernel)
  STG_A(0, 0, 0) STG_B(0, 0, 0) STG_B(0, 1, 0) STG_A(0, 1, 0)
  asm volatile("s_waitcnt vmcnt(0)\n\ts_barrier" ::: "memory");

  for (int t = 0; t < nt; t++) {
    const int bu = t & 1, bn = bu ^ 1;
    const bool pf = (t + 1 < nt);
    bf16x8 fa[2][4], fb[2][2];
    // P1 (0,0): fresh fa + fb; stage Ah0(t+1)
    RD_A(fa, bu, 0)
    RD_B(fb, bu, 0)
    if (pf) STG_A(bn, 0, t + 1)
    PH_MFMA(0, 0)
    // P2 (0,1): reuse fa, read Bh1; stage Bh1(t+1)
    RD_B(fb, bu, 1)
    if (pf) STG_B(bn, 1, t + 1)
    PH_MFMA(0, 1)
    if (pf) asm volatile("s_waitcnt vmcnt(4)\n\ts_barrier" ::: "memory");
    else    asm volatile("s_waitcnt vmcnt(0)\n\ts_barrier" ::: "memory");
    // P3 (1,1): reuse fb, read Ah1; stage Bh0(t+1)
    RD_A(fa, bu, 1)
    if (pf) STG_B(bn, 0, t + 1)
    PH_MFMA(1, 1)
    // P4 (1,0): reuse fa, read Bh0; stage Ah1(t+1)
    RD_B(fb, bu, 0)
    if (pf) STG_A(bn, 1, t + 1)
    PH_MFMA(1, 0)
    if (pf) asm volatile("s_waitcnt vmcnt(2)\n\ts_barrier" ::: "memory");
  }
#undef STG1
#undef STG_A
#undef STG_B
#undef RD_A
#undef RD_B
#undef PH_MFMA

  const long zoff = (long)blockIdx.z * (long)M * (long)N;
  if (VT && n0 >= 2048) {
    // V-half of the KV GEMM: write transposed into Vt[bh*128+d][s]
#pragma unroll
    for (int a = 0; a < 2; a++) {
#pragma unroll
      for (int b = 0; b < 2; b++) {
#pragma unroll
        for (int i = 0; i < 4; i++) {
#pragma unroll
          for (int j = 0; j < 2; j++) {
            const int row0 = m0 + a * 128 + sr + i * 16 + g * 4;
            const int col2 = n0 + b * 128 + sc + j * 16 + lrow - 2048;
            const int hh = col2 >> 7, dd = col2 & 127;
            const int batch = row0 >> 11, sseq = row0 & 2047;
            ushort4 o;
            o.x = f2bf(acc[a][b][i][j][0]);
            o.y = f2bf(acc[a][b][i][j][1]);
            o.z = f2bf(acc[a][b][i][j][2]);
            o.w = f2bf(acc[a][b][i][j][3]);
            *reinterpret_cast<ushort4*>(
                VtOut + ((long)((batch * 16 + hh) * 128 + dd)) * 2048 + sseq) = o;
          }
        }
      }
    }
    return;
  }
#pragma unroll
  for (int a = 0; a < 2; a++) {
#pragma unroll
    for (int b = 0; b < 2; b++) {
#pragma unroll
      for (int i = 0; i < 4; i++) {
#pragma unroll
        for (int j = 0; j < 2; j++) {
          const int row = m0 + a * 128 + sr + i * 16 + g * 4;
          const int col = n0 + b * 128 + sc + j * 16 + lrow;
          float bv = 0.f;
          if (BIAS) bv = bias[col];
#pragma unroll
          for (int r = 0; r < 4; r++) {
            float v = acc[a][b][i][j][r];
            if (BIAS) v += bv;
            if (RELU) v = fmaxf(v, 0.f);
            const long idx = zoff + (long)(row + r) * N + col;
            if (OBF16) ((unsigned short*)Cout)[idx] = f2bf(v);
            else       ((float*)Cout)[idx] = v;
          }
        }
      }
    }
  }
}

// ---------------------------------------------------------------------------
// combine split-K partials: out = p0 + p1 [+ bias[col]] + res  (f32)
// ---------------------------------------------------------------------------
template <bool BIAS>
__global__ __launch_bounds__(256) void combine2(
    const unsigned short* __restrict__ p, const float* __restrict__ bias,
    const float* __restrict__ res, float* __restrict__ out, long n) {
  const long i = ((long)blockIdx.x * 256 + threadIdx.x) * 4;
  if (i >= n) return;
  const ushort4 a = *reinterpret_cast<const ushort4*>(p + i);
  const ushort4 b = *reinterpret_cast<const ushort4*>(p + n + i);
  const float4 r = *reinterpret_cast<const float4*>(res + i);
  float4 o;
  o.x = bf2f(a.x) + bf2f(b.x) + r.x;
  o.y = bf2f(a.y) + bf2f(b.y) + r.y;
  o.z = bf2f(a.z) + bf2f(b.z) + r.z;
  o.w = bf2f(a.w) + bf2f(b.w) + r.w;
  if (BIAS) {
    const int col = (int)(i & 2047);
    const float4 bv = *reinterpret_cast<const float4*>(bias + col);
    o.x += bv.x; o.y += bv.y; o.z += bv.z; o.w += bv.w;
  }
  *reinterpret_cast<float4*>(out + i) = o;
}

// ---------------------------------------------------------------------------
// Causal flash attention, KVBLK=64 (serial q-tile pair, 80 VGPR — the
// measured-best version; R14's merged pair cost 140 VGPR -> occupancy
// 10.8% -> +55 us. Do not merge states without a VGPR budget).
// ---------------------------------------------------------------------------
__global__ __launch_bounds__(256) void flash_attn(
    const unsigned short* __restrict__ Q, const unsigned short* __restrict__ KV,
    const unsigned short* __restrict__ Vt, unsigned short* __restrict__ O) {
  constexpr int S = 2048;
  const int tid = threadIdx.x, lane = tid & 63, w = tid >> 6;
  const int g = lane >> 4, lcol = lane & 15;
  const int wg = blockIdx.x;              // 0..511
  const int x8 = wg & 7, q64 = wg >> 3;   // q64 0..63
  const int p = q64 & 15, hi = q64 >> 4;
  const int bh = x8 * 4 + hi;             // 0..31
  const int b = bh >> 4, h = bh & 15;
  const long kvrow0 = (long)b * S;
  const int hd0 = h * 128;

  __shared__ __align__(16) unsigned short Kl[64 * 128];   // [k][d] swizzled
  __shared__ __align__(16) unsigned short Vl[128 * 64];   // [d][k] swizzled
  __shared__ __align__(16) unsigned short Pl[4 * 16 * 72];

  const float kscale = 0.08838834764831845f * 1.4426950408889634f; // /sqrt(128)*log2e

  for (int ti = 0; ti < 2; ti++) {
    const int t = ti ? (31 - p) : p;
    const int qbase = t * 64;
    bf16x8 qf[4];
#pragma unroll
    for (int dc = 0; dc < 4; dc++)
      qf[dc] = *reinterpret_cast<const bf16x8*>(
          Q + (kvrow0 + qbase + w * 16 + lcol) * 2048 + hd0 + dc * 32 + g * 8);
    f32x4 oacc[8] = {};
    float mst[4] = {NEG_INF, NEG_INF, NEG_INF, NEG_INF};
    float lst[4] = {0.f, 0.f, 0.f, 0.f};
    const int nk = t + 1;
    for (int kt = 0; kt < nk; kt++) {
      const int kv0 = kt * 64;
      __syncthreads();
#pragma unroll
      for (int i = 0; i < 4; i++) {
        const int o16 = i * 256 + tid;
        const int kr = o16 >> 4, ks = o16 & 15;
        GLDS16(KV + (kvrow0 + kv0 + kr) * 4096 + hd0 + 8 * (ks ^ (kr & 7)),
               Kl + o16 * 8);
        const int vd = o16 >> 3, vs = o16 & 7;
        GLDS16(Vt + ((long)bh * 128 + vd) * 2048 + kv0 + 8 * (vs ^ (vd & 7)),
               Vl + o16 * 8);
      }
      __syncthreads();
      // QK^T: 16q x 64k
      f32x4 sc[4] = {};
      __builtin_amdgcn_s_setprio(1);
#pragma unroll
      for (int dc = 0; dc < 4; dc++) {
#pragma unroll
        for (int c = 0; c < 4; c++) {
          const bf16x8 kf = *reinterpret_cast<const bf16x8*>(
              Kl + (c * 16 + lcol) * 128 + 8 * ((4 * dc + g) ^ (lcol & 7)));
          sc[c] = __builtin_amdgcn_mfma_f32_16x16x32_bf16(qf[dc], kf, sc[c], 0, 0, 0);
        }
      }
      __builtin_amdgcn_s_setprio(0);
      float s[4][4];
      const int qrow = qbase + w * 16 + g * 4;
      if (kt == nk - 1) {
#pragma unroll
        for (int c = 0; c < 4; c++) {
          const int col = kv0 + c * 16 + lcol;
#pragma unroll
          for (int r = 0; r < 4; r++)
            s[c][r] = (col <= qrow + r) ? sc[c][r] * kscale : NEG_INF;
        }
      } else {
#pragma unroll
        for (int c = 0; c < 4; c++)
#pragma unroll
          for (int r = 0; r < 4; r++) s[c][r] = sc[c][r] * kscale;
      }
      float pm[4];
#pragma unroll
      for (int r = 0; r < 4; r++) {
        float mx = fmaxf(fmaxf(s[0][r], s[1][r]), fmaxf(s[2][r], s[3][r]));
        mx = fmaxf(mx, __shfl_xor(mx, 1));
        mx = fmaxf(mx, __shfl_xor(mx, 2));
        mx = fmaxf(mx, __shfl_xor(mx, 4));
        mx = fmaxf(mx, __shfl_xor(mx, 8));
        pm[r] = mx;
      }
      bool need = false;
#pragma unroll
      for (int r = 0; r < 4; r++) need = need || (pm[r] > mst[r] + 11.5f);
      if (__any(need)) {
#pragma unroll
        for (int r = 0; r < 4; r++) {
          const float mnew = fmaxf(mst[r], pm[r]);
          const float corr = exp2f(mst[r] - mnew);
          mst[r] = mnew;
          lst[r] *= corr;
#pragma unroll
          for (int db = 0; db < 8; db++) oacc[db][r] *= corr;
        }
      }
#pragma unroll
      for (int r = 0; r < 4; r++) {
        float ps = 0.f;
#pragma unroll
        for (int c = 0; c < 4; c++) {
          const float pv = exp2f(s[c][r] - mst[r]);
          Pl[(w * 16 + g * 4 + r) * 72 + c * 16 + lcol] = f2bf(pv);
          ps += pv;
        }
        ps += __shfl_xor(ps, 1); ps += __shfl_xor(ps, 2);
        ps += __shfl_xor(ps, 4); ps += __shfl_xor(ps, 8);
        lst[r] += ps;
      }
      __builtin_amdgcn_s_setprio(1);
#pragma unroll
      for (int kk = 0; kk < 2; kk++) {
        const bf16x8 pf = *reinterpret_cast<const bf16x8*>(
            Pl + (w * 16 + lcol) * 72 + kk * 32 + g * 8);
#pragma unroll
        for (int db = 0; db < 8; db++) {
          const bf16x8 vf = *reinterpret_cast<const bf16x8*>(
              Vl + (db * 16 + lcol) * 64 + 8 * ((4 * kk + g) ^ (lcol & 7)));
          oacc[db] = __builtin_amdgcn_mfma_f32_16x16x32_bf16(pf, vf, oacc[db], 0, 0, 0);
        }
      }
      __builtin_amdgcn_s_setprio(0);
    }
#pragma unroll
    for (int db = 0; db < 8; db++)
#pragma unroll
      for (int r = 0; r < 4; r++) {
        const int qi = qbase + w * 16 + g * 4 + r;
        O[(kvrow0 + qi) * 2048 + hd0 + db * 16 + lcol] = f2bf(oacc[db][r] / lst[r]);
      }
  }
}

// ---------------------------------------------------------------------------
// launch
// ---------------------------------------------------------------------------
extern "C" void kernel_launch(void* const* d_in, const int* in_sizes, int n_in,
                              void* d_out, int out_size, void* d_ws, size_t ws_size,
                              hipStream_t stream) {
  (void)in_sizes; (void)n_in; (void)out_size; (void)ws_size;
  const float* x     = (const float*)d_in[0];
  const float* W_dq  = (const float*)d_in[1];
  const float* W_uq  = (const float*)d_in[2];
  const float* qlng  = (const float*)d_in[3];
  const float* qlnb  = (const float*)d_in[4];
  const float* W_dkv = (const float*)d_in[5];
  const float* W_ukv = (const float*)d_in[6];
  const float* klng  = (const float*)d_in[7];
  const float* klnb  = (const float*)d_in[8];
  const float* W_o   = (const float*)d_in[9];
  const float* n1g   = (const float*)d_in[10];
  const float* n1b   = (const float*)d_in[11];
  const float* n2g   = (const float*)d_in[12];
  const float* n2b   = (const float*)d_in[13];
  const float* fc1w  = (const float*)d_in[14];
  const float* fc1b  = (const float*)d_in[15];
  const float* fc2w  = (const float*)d_in[16];
  const float* fc2b  = (const float*)d_in[17];
  float* out = (float*)d_out;

  char* ws = (char*)d_ws;
  // region A [0,32M): normed -> Obuf -> fc2bb
  unsigned short* normed = (unsigned short*)(ws + 0);
  unsigned short* Obuf   = (unsigned short*)(ws + 0);
  unsigned short* fc2bb  = (unsigned short*)(ws + 0);
  // region B [32M,64M): cqkv_part (4x8MB bf16) -> KV -> fc1bb -> fc2part
  unsigned short* cqkv_part = (unsigned short*)(ws + 33554432);
  unsigned short* KV        = (unsigned short*)(ws + 33554432);
  unsigned short* fc1bb     = (unsigned short*)(ws + 33554432);
  unsigned short* fc2part   = (unsigned short*)(ws + 33554432);
  // region C [64M,68M): cq
  unsigned short* cq  = (unsigned short*)(ws + 67108864);
  // region D [68M,84.7M): Qb -> h1
  unsigned short* Qb = (unsigned short*)(ws + 71303168);
  unsigned short* h1 = (unsigned short*)(ws + 71303168);
  // region E [84M,117.6M): ckv (early) -> x2 (late)
  unsigned short* ckv = (unsigned short*)(ws + 88080384);
  float* x2           = (float*)(ws + 88080384);
  // region F [116M,180M): Vt -> wopart -> hmid
  unsigned short* Vtb    = (unsigned short*)(ws + 121634816);
  unsigned short* wopart = (unsigned short*)(ws + 121634816);
  unsigned short* hmid   = (unsigned short*)(ws + 121634816);
  // region G [180M,...): transposed/cast weights
  unsigned short* dqkv_t = (unsigned short*)(ws + 188743680);  // 1024 x 2048
  unsigned short* uq_t   = dqkv_t + 2097152;                   // 2048 x 512
  unsigned short* ukv_t  = uq_t + 1048576;                     // 4096 x 512
  unsigned short* wo_b   = ukv_t + 2097152;                    // 2048 x 2048

  const dim3 blk(256);
  const dim3 blk8(512);

  // all weight transposes + W_o cast in one launch
  weight_prep<<<9216, blk, 0, stream>>>(W_dq, W_dkv, W_uq, W_ukv, W_o,
                                        dqkv_t, uq_t, ukv_t, wo_b);

  // LN1
  layernorm_bf16<2048><<<4096, blk, 0, stream>>>(x, n1g, n1b, normed, 2048);
  // cqkv partials = normed @ [W_dq | W_dkv]  (split-K=4, bf16 partials)
  gemm256p<false, false, true, false><<<dim3(16, 4, 4), blk8, 0, stream>>>(
      normed, dqkv_t, nullptr, cqkv_part, nullptr, 4096, 1024, 2048, 2048, 512, 512);
  // cq / ckv = LN over summed partials (one launch, no combine pass)
  ln2x512<<<4096, blk, 0, stream>>>(cqkv_part, qlng, qlnb, klng, klnb, cq, ckv);
  // Q = cq @ W_uq
  gemm_bt<false, false, false, true><<<dim3(32, 16), blk, 0, stream>>>(
      cq, uq_t, nullptr, nullptr, Qb, 4096, 2048, 512);
  // KV = ckv @ W_ukv ; V half written transposed into Vt (fused v_transpose)
  gemm256p<false, false, true, true><<<dim3(16, 16), blk8, 0, stream>>>(
      ckv, ukv_t, nullptr, KV, Vtb, 4096, 4096, 512, 512, 512, 0);
  // attention (serial q-tile pairs, 80-VGPR version)
  flash_attn<<<dim3(512), blk, 0, stream>>>(Qb, KV, Vtb, Obuf);
  // W_o partials: split-K=2 (Vt dead -> region F)
  gemm256p<false, false, true, false><<<dim3(16, 8, 2), blk8, 0, stream>>>(
      Obuf, wo_b, nullptr, wopart, nullptr, 4096, 2048, 2048, 2048, 1024, 1024);
  // fc1 + fc2 weight casts (regions B and A both free now), one launch
  cast2_f32_bf16<<<32768, blk, 0, stream>>>(fc1w, fc1bb, 16777216L, fc2w, fc2bb);
  // x2 = x + p0 + p1 ; h1 = LN(x2)   (fused)
  combine_ln<<<4096, blk, 0, stream>>>(wopart, x, n2g, n2b, x2, h1, 8388608L);
  // h_mid = relu(h1 @ fc1^T + b1)
  gemm256p<true, true, true, false><<<dim3(16, 32), blk8, 0, stream>>>(
      h1, fc1bb, fc1b, hmid, nullptr, 4096, 8192, 2048, 2048, 2048, 0);
  // fc2 partials: split-K=2
  gemm256p<false, false, true, false><<<dim3(16, 8, 2), blk8, 0, stream>>>(
      hmid, fc2bb, nullptr, fc2part, nullptr, 4096, 2048, 8192, 8192, 4096, 4096);
  // out = p0 + p1 + b2 + x2
  combine2<true><<<8192, blk, 0, stream>>>(fc2part, fc2b, x2, out, 8388608L);
}

// Round 17
// 519.798 us; speedup vs baseline: 1.1323x; 1.0080x over previous
//
#include <hip/hip_runtime.h>
#include <hip/hip_bf16.h>

// ---------------------------------------------------------------------------
// TransformerDecoderBlock (MLA-style) for MI355X / gfx950
// B=2 S=2048 D=2048 NH=16 DH=128 LAT=512
// ---------------------------------------------------------------------------

#define DEVI __device__ __forceinline__

typedef __attribute__((ext_vector_type(8))) short bf16x8;
typedef __attribute__((ext_vector_type(4))) float f32x4;

DEVI unsigned short f2bf(float f) {
  union { float f; unsigned u; } v; v.f = f;
  unsigned r = v.u + 0x7fffu + ((v.u >> 16) & 1u);
  return (unsigned short)(r >> 16);
}

DEVI float bf2f(unsigned short u) {
  union { unsigned u; float f; } v; v.u = ((unsigned)u) << 16;
  return v.f;
}

#define GLDS16(gp, lp)                                              \
  __builtin_amdgcn_global_load_lds(                                 \
      (__attribute__((address_space(1))) void*)(gp),                \
      (__attribute__((address_space(3))) void*)(lp), 16, 0, 0)

#define NEG_INF (-__builtin_inff())

// ---------------------------------------------------------------------------
// cast2: fc1 (n1 elems) then fc2 weights in one launch; block-uniform split.
// ---------------------------------------------------------------------------
__global__ __launch_bounds__(256) void cast2_f32_bf16(
    const float* __restrict__ in1, unsigned short* __restrict__ out1, long n1,
    const float* __restrict__ in2, unsigned short* __restrict__ out2) {
  long i = ((long)blockIdx.x * 256 + threadIdx.x) * 4;
  const float* in = in1;
  unsigned short* out = out1;
  if (i >= n1) { i -= n1; in = in2; out = out2; }
  const float4 v = *reinterpret_cast<const float4*>(in + i);
  ushort4 o;
  o.x = f2bf(v.x); o.y = f2bf(v.y); o.z = f2bf(v.z); o.w = f2bf(v.w);
  *reinterpret_cast<ushort4*>(out + i) = o;
}

// ---------------------------------------------------------------------------
// weight_prep: one launch for all weight transforms.
// ---------------------------------------------------------------------------
__global__ __launch_bounds__(256) void weight_prep(
    const float* __restrict__ W_dq, const float* __restrict__ W_dkv,
    const float* __restrict__ W_uq, const float* __restrict__ W_ukv,
    const float* __restrict__ W_o, unsigned short* __restrict__ dqkv_t,
    unsigned short* __restrict__ uq_t, unsigned short* __restrict__ ukv_t,
    unsigned short* __restrict__ wo_b) {
  __shared__ float tile[32][33];
  const int id = blockIdx.x;
  const int tx = threadIdx.x & 31, ty = threadIdx.x >> 5;  // ty 0..7
  const float* in;
  unsigned short* out;
  int R, C, bx, by;
  if (id < 1024) {
    in = W_dq; out = dqkv_t; R = 2048; C = 512; bx = id & 15; by = id >> 4;
  } else if (id < 2048) {
    const int t = id - 1024;
    in = W_dkv; out = dqkv_t + 512 * 2048; R = 2048; C = 512; bx = t & 15; by = t >> 4;
  } else if (id < 3072) {
    const int t = id - 2048;
    in = W_uq; out = uq_t; R = 512; C = 2048; bx = t & 63; by = t >> 6;
  } else if (id < 5120) {
    const int t = id - 3072;
    in = W_ukv; out = ukv_t; R = 512; C = 4096; bx = t & 127; by = t >> 7;
  } else {
    const long i = ((long)(id - 5120) * 256 + threadIdx.x) * 4;
    const float4 v = *reinterpret_cast<const float4*>(W_o + i);
    ushort4 o;
    o.x = f2bf(v.x); o.y = f2bf(v.y); o.z = f2bf(v.z); o.w = f2bf(v.w);
    *reinterpret_cast<ushort4*>(wo_b + i) = o;
    return;
  }
  const int c0 = bx * 32, r0 = by * 32;
#pragma unroll
  for (int i = 0; i < 32; i += 8)
    tile[ty + i][tx] = in[(long)(r0 + ty + i) * C + c0 + tx];
  __syncthreads();
#pragma unroll
  for (int i = 0; i < 32; i += 8)
    out[(long)(c0 + ty + i) * R + r0 + tx] = f2bf(tile[tx][ty + i]);
}

// ---------------------------------------------------------------------------
// block reduce (256 threads = 4 waves)
// ---------------------------------------------------------------------------
DEVI float blockReduceSum(float v) {
  v += __shfl_xor(v, 1);  v += __shfl_xor(v, 2);  v += __shfl_xor(v, 4);
  v += __shfl_xor(v, 8);  v += __shfl_xor(v, 16); v += __shfl_xor(v, 32);
  __shared__ float red[4];
  if ((threadIdx.x & 63) == 0) red[threadIdx.x >> 6] = v;
  __syncthreads();
  v = red[0] + red[1] + red[2] + red[3];
  __syncthreads();
  return v;
}

// ---------------------------------------------------------------------------
// LayerNorm over W cols, one block (256 thr) per row; input row stride ldin.
// ---------------------------------------------------------------------------
template <int W>
__global__ __launch_bounds__(256) void layernorm_bf16(
    const float* __restrict__ in, const float* __restrict__ g,
    const float* __restrict__ b, unsigned short* __restrict__ out, int ldin) {
  constexpr int VPT = W / 256;
  const long row = blockIdx.x;
  const float* x = in + row * ldin;
  float v[VPT];
  float s = 0.f;
#pragma unroll
  for (int i = 0; i < VPT; i++) { v[i] = x[threadIdx.x + i * 256]; s += v[i]; }
  s = blockReduceSum(s);
  const float mean = s * (1.0f / W);
  float s2 = 0.f;
#pragma unroll
  for (int i = 0; i < VPT; i++) { float d = v[i] - mean; s2 += d * d; }
  s2 = blockReduceSum(s2);
  const float rstd = rsqrtf(s2 * (1.0f / W) + 1e-5f);
#pragma unroll
  for (int i = 0; i < VPT; i++) {
    const int c = threadIdx.x + i * 256;
    out[row * W + c] = f2bf((v[i] - mean) * rstd * g[c] + b[c]);
  }
}

// ---------------------------------------------------------------------------
// ln2x512: both 512-wide LayerNorms of one cqkv row in ONE launch, reading
// 4 split-K bf16 partials (p + z*PN) and summing them (no combine pass).
// ---------------------------------------------------------------------------
__global__ __launch_bounds__(256) void ln2x512(
    const unsigned short* __restrict__ part, const float* __restrict__ g1,
    const float* __restrict__ b1, const float* __restrict__ g2,
    const float* __restrict__ b2, unsigned short* __restrict__ cq,
    unsigned short* __restrict__ ckv) {
  constexpr long PN = 4096L * 1024;
  const long row = blockIdx.x;
  const int tid = threadIdx.x;
  const int half = tid >> 7, lt = tid & 127;
  __shared__ float red[8];
  const long off = row * 1024 + half * 512 + lt * 4;
  const ushort4 a0 = *reinterpret_cast<const ushort4*>(part + off);
  const ushort4 a1 = *reinterpret_cast<const ushort4*>(part + PN + off);
  const ushort4 a2 = *reinterpret_cast<const ushort4*>(part + 2 * PN + off);
  const ushort4 a3 = *reinterpret_cast<const ushort4*>(part + 3 * PN + off);
  float4 v;
  v.x = bf2f(a0.x) + bf2f(a1.x) + bf2f(a2.x) + bf2f(a3.x);
  v.y = bf2f(a0.y) + bf2f(a1.y) + bf2f(a2.y) + bf2f(a3.y);
  v.z = bf2f(a0.z) + bf2f(a1.z) + bf2f(a2.z) + bf2f(a3.z);
  v.w = bf2f(a0.w) + bf2f(a1.w) + bf2f(a2.w) + bf2f(a3.w);
  float s = v.x + v.y + v.z + v.w;
  s += __shfl_xor(s, 1);  s += __shfl_xor(s, 2);  s += __shfl_xor(s, 4);
  s += __shfl_xor(s, 8);  s += __shfl_xor(s, 16); s += __shfl_xor(s, 32);
  if ((tid & 63) == 0) red[tid >> 6] = s;
  __syncthreads();
  const float mean = (red[half * 2] + red[half * 2 + 1]) * (1.f / 512.f);
  const float d0 = v.x - mean, d1 = v.y - mean, d2 = v.z - mean, d3 = v.w - mean;
  float s2 = d0 * d0 + d1 * d1 + d2 * d2 + d3 * d3;
  s2 += __shfl_xor(s2, 1);  s2 += __shfl_xor(s2, 2);  s2 += __shfl_xor(s2, 4);
  s2 += __shfl_xor(s2, 8);  s2 += __shfl_xor(s2, 16); s2 += __shfl_xor(s2, 32);
  if ((tid & 63) == 0) red[4 + (tid >> 6)] = s2;
  __syncthreads();
  const float rstd = rsqrtf((red[4 + half * 2] + red[5 + half * 2]) * (1.f / 512.f) + 1e-5f);
  const float* g = half ? g2 : g1;
  const float* b = half ? b2 : b1;
  const float4 gv = *reinterpret_cast<const float4*>(g + lt * 4);
  const float4 bv = *reinterpret_cast<const float4*>(b + lt * 4);
  ushort4 o;
  o.x = f2bf(d0 * rstd * gv.x + bv.x);
  o.y = f2bf(d1 * rstd * gv.y + bv.y);
  o.z = f2bf(d2 * rstd * gv.z + bv.z);
  o.w = f2bf(d3 * rstd * gv.w + bv.w);
  *reinterpret_cast<ushort4*>((half ? ckv : cq) + row * 512 + lt * 4) = o;
}

// ---------------------------------------------------------------------------
// combine_ln: fused W_o-combine (2 split-K partials) + residual + LN (W=2048).
// ---------------------------------------------------------------------------
__global__ __launch_bounds__(256) void combine_ln(
    const unsigned short* __restrict__ p, const float* __restrict__ xres,
    const float* __restrict__ g, const float* __restrict__ b,
    float* __restrict__ x2, unsigned short* __restrict__ h1, long n) {
  const int c0 = threadIdx.x * 8;
  const long base = (long)blockIdx.x * 2048 + c0;
  float v[8];
  float s = 0.f;
#pragma unroll
  for (int hh = 0; hh < 2; hh++) {
    const long i = base + hh * 4;
    const ushort4 a  = *reinterpret_cast<const ushort4*>(p + i);
    const ushort4 bb = *reinterpret_cast<const ushort4*>(p + n + i);
    const float4 r = *reinterpret_cast<const float4*>(xres + i);
    float4 o;
    o.x = r.x + bf2f(a.x) + bf2f(bb.x);
    o.y = r.y + bf2f(a.y) + bf2f(bb.y);
    o.z = r.z + bf2f(a.z) + bf2f(bb.z);
    o.w = r.w + bf2f(a.w) + bf2f(bb.w);
    *reinterpret_cast<float4*>(x2 + i) = o;
    v[hh * 4 + 0] = o.x; v[hh * 4 + 1] = o.y;
    v[hh * 4 + 2] = o.z; v[hh * 4 + 3] = o.w;
    s += o.x + o.y + o.z + o.w;
  }
  s = blockReduceSum(s);
  const float mean = s * (1.0f / 2048.f);
  float s2 = 0.f;
#pragma unroll
  for (int i = 0; i < 8; i++) { float d = v[i] - mean; s2 += d * d; }
  s2 = blockReduceSum(s2);
  const float rstd = rsqrtf(s2 * (1.0f / 2048.f) + 1e-5f);
#pragma unroll
  for (int hh = 0; hh < 2; hh++) {
    const float4 gv = *reinterpret_cast<const float4*>(g + c0 + hh * 4);
    const float4 bv = *reinterpret_cast<const float4*>(b + c0 + hh * 4);
    ushort4 o;
    o.x = f2bf((v[hh * 4 + 0] - mean) * rstd * gv.x + bv.x);
    o.y = f2bf((v[hh * 4 + 1] - mean) * rstd * gv.y + bv.y);
    o.z = f2bf((v[hh * 4 + 2] - mean) * rstd * gv.z + bv.z);
    o.w = f2bf((v[hh * 4 + 3] - mean) * rstd * gv.w + bv.w);
    *reinterpret_cast<ushort4*>(h1 + base + hh * 4) = o;
  }
}

// ---------------------------------------------------------------------------
// gemm256p: R10-exact 4-phase pipelined 256x256 GEMM, BK=64, 8 waves.
// BEST MEASURED configuration (fc1 ~126 us, MfmaUtil 47.3%, 0 conflicts,
// VGPR 104). Structure plateau — do not revisit without new counter
// evidence (see R7/R8/R11/R12 failure notes in history).
// VT flag: KV-GEMM blocks with n0>=2048 write V transposed into Vt.
// MIX flag: blocks with blockIdx.y>=16 compute the Q-up GEMM instead
// (Bt2=uq_t, Cout2=Qb, N=2048) — both GEMMs share K=512 / lda=ldb=512,
// so one launch covers KV+V^T+Q (384 blocks, block-uniform decode).
// ---------------------------------------------------------------------------
template <bool BIAS, bool RELU, bool OBF16, bool VT, bool MIX>
__global__ __launch_bounds__(512, 1) void gemm256p(
    const unsigned short* __restrict__ A, const unsigned short* __restrict__ Bt,
    const float* __restrict__ bias, void* __restrict__ Cout,
    unsigned short* __restrict__ VtOut,
    const unsigned short* __restrict__ A2, const unsigned short* __restrict__ Bt2,
    void* __restrict__ Cout2,
    int M, int N, int lda, int ldb, int kLen, long kOff) {
  __shared__ __align__(16) unsigned short L[2][2][2][256 * 32];

  const int m0 = blockIdx.x * 256;
  int n0 = blockIdx.y * 256;
  int Nn = N;
  const unsigned short* Ap = A;
  const unsigned short* Btp = Bt;
  void* Coutp = Cout;
  bool isQ = false;
  if (MIX && blockIdx.y >= 16) {
    isQ = true;
    Ap = A2; Btp = Bt2; Coutp = Cout2;
    n0 = (blockIdx.y - 16) * 256;
    Nn = 2048;
  }
  const long ka = (long)blockIdx.z * kOff;
  const int tid = threadIdx.x;
  const int lane = tid & 63, w = tid >> 6;
  const int sr = (w >> 2) * 64, sc = (w & 3) * 32;
  const int g = lane >> 4, lrow = lane & 15;
  const int r_ = tid >> 2, s_ = tid & 3;

  f32x4 acc[2][2][4][2] = {};
  const int nt = kLen >> 6;

#define STG1(bb, ab, h, kh, t, P, base0, ld)                                   \
  {                                                                            \
    const long k0 = ka + (long)(t) * 64 + (kh) * 32;                           \
    const int rr = (h) * 128 + r_;                                             \
    GLDS16((P) + (long)((base0) + rr) * (ld) + k0 + ((s_ ^ ((rr >> 1) & 3)) << 3), \
           &L[bb][ab][kh][((h) * 512 + tid) * 8]);                             \
  }
#define STG_A(bb, h, t) STG1(bb, 0, h, 0, t, Ap, m0, lda) STG1(bb, 0, h, 1, t, Ap, m0, lda)
#define STG_B(bb, h, t) STG1(bb, 1, h, 0, t, Btp, n0, ldb) STG1(bb, 1, h, 1, t, Btp, n0, ldb)

#define RD_A(fa, bu, a)                                                        \
  _Pragma("unroll")                                                            \
  for (int kh = 0; kh < 2; kh++)                                               \
    _Pragma("unroll")                                                          \
    for (int i = 0; i < 4; i++) {                                              \
      const int rr = (a) * 128 + sr + i * 16 + lrow;                           \
      fa[kh][i] = *reinterpret_cast<const bf16x8*>(                            \
          &L[bu][0][kh][(rr * 4 + (g ^ ((rr >> 1) & 3))) * 8]);                \
    }
#define RD_B(fb, bu, b)                                                        \
  _Pragma("unroll")                                                            \
  for (int kh = 0; kh < 2; kh++)                                               \
    _Pragma("unroll")                                                          \
    for (int j = 0; j < 2; j++) {                                              \
      const int rr = (b) * 128 + sc + j * 16 + lrow;                           \
      fb[kh][j] = *reinterpret_cast<const bf16x8*>(                            \
          &L[bu][1][kh][(rr * 4 + (g ^ ((rr >> 1) & 3))) * 8]);                \
    }

#define PH_MFMA(a, b)                                                          \
  __builtin_amdgcn_s_setprio(1);                                               \
  _Pragma("unroll")                                                            \
  for (int kh = 0; kh < 2; kh++)                                               \
    _Pragma("unroll")                                                          \
    for (int i = 0; i < 4; i++)                                                \
      _Pragma("unroll")                                                        \
      for (int j = 0; j < 2; j++)                                              \
        acc[a][b][i][j] = __builtin_amdgcn_mfma_f32_16x16x32_bf16(             \
            fa[kh][i], fb[kh][j], acc[a][b][i][j], 0, 0, 0);                   \
  __builtin_amdgcn_s_setprio(0);

  // prologue: tile 0 -> buf 0, full drain (once per kernel)
  STG_A(0, 0, 0) STG_B(0, 0, 0) STG_B(0, 1, 0) STG_A(0, 1, 0)
  asm volatile("s_waitcnt vmcnt(0)\n\ts_barrier" ::: "memory");

  for (int t = 0; t < nt; t++) {
    const int bu = t & 1, bn = bu ^ 1;
    const bool pf = (t + 1 < nt);
    bf16x8 fa[2][4], fb[2][2];
    // P1 (0,0): fresh fa + fb; stage Ah0(t+1)
    RD_A(fa, bu, 0)
    RD_B(fb, bu, 0)
    if (pf) STG_A(bn, 0, t + 1)
    PH_MFMA(0, 0)
    // P2 (0,1): reuse fa, read Bh1; stage Bh1(t+1)
    RD_B(fb, bu, 1)
    if (pf) STG_B(bn, 1, t + 1)
    PH_MFMA(0, 1)
    if (pf) asm volatile("s_waitcnt vmcnt(4)\n\ts_barrier" ::: "memory");
    else    asm volatile("s_waitcnt vmcnt(0)\n\ts_barrier" ::: "memory");
    // P3 (1,1): reuse fb, read Ah1; stage Bh0(t+1)
    RD_A(fa, bu, 1)
    if (pf) STG_B(bn, 0, t + 1)
    PH_MFMA(1, 1)
    // P4 (1,0): reuse fa, read Bh0; stage Ah1(t+1)
    RD_B(fb, bu, 0)
    if (pf) STG_A(bn, 1, t + 1)
    PH_MFMA(1, 0)
    if (pf) asm volatile("s_waitcnt vmcnt(2)\n\ts_barrier" ::: "memory");
  }
#undef STG1
#undef STG_A
#undef STG_B
#undef RD_A
#undef RD_B
#undef PH_MFMA

  const long zoff = (long)blockIdx.z * (long)M * (long)Nn;
  if (VT && !isQ && n0 >= 2048) {
    // V-half of the KV GEMM: write transposed into Vt[bh*128+d][s]
#pragma unroll
    for (int a = 0; a < 2; a++) {
#pragma unroll
      for (int b = 0; b < 2; b++) {
#pragma unroll
        for (int i = 0; i < 4; i++) {
#pragma unroll
          for (int j = 0; j < 2; j++) {
            const int row0 = m0 + a * 128 + sr + i * 16 + g * 4;
            const int col2 = n0 + b * 128 + sc + j * 16 + lrow - 2048;
            const int hh = col2 >> 7, dd = col2 & 127;
            const int batch = row0 >> 11, sseq = row0 & 2047;
            ushort4 o;
            o.x = f2bf(acc[a][b][i][j][0]);
            o.y = f2bf(acc[a][b][i][j][1]);
            o.z = f2bf(acc[a][b][i][j][2]);
            o.w = f2bf(acc[a][b][i][j][3]);
            *reinterpret_cast<ushort4*>(
                VtOut + ((long)((batch * 16 + hh) * 128 + dd)) * 2048 + sseq) = o;
          }
        }
      }
    }
    return;
  }
#pragma unroll
  for (int a = 0; a < 2; a++) {
#pragma unroll
    for (int b = 0; b < 2; b++) {
#pragma unroll
      for (int i = 0; i < 4; i++) {
#pragma unroll
        for (int j = 0; j < 2; j++) {
          const int row = m0 + a * 128 + sr + i * 16 + g * 4;
          const int col = n0 + b * 128 + sc + j * 16 + lrow;
          float bv = 0.f;
          if (BIAS) bv = bias[col];
#pragma unroll
          for (int r = 0; r < 4; r++) {
            float v = acc[a][b][i][j][r];
            if (BIAS) v += bv;
            if (RELU) v = fmaxf(v, 0.f);
            const long idx = zoff + (long)(row + r) * Nn + col;
            if (OBF16) ((unsigned short*)Coutp)[idx] = f2bf(v);
            else       ((float*)Coutp)[idx] = v;
          }
        }
      }
    }
  }
}

// ---------------------------------------------------------------------------
// combine split-K partials: out = p0 + p1 [+ bias[col]] + res  (f32)
// ---------------------------------------------------------------------------
template <bool BIAS>
__global__ __launch_bounds__(256) void combine2(
    const unsigned short* __restrict__ p, const float* __restrict__ bias,
    const float* __restrict__ res, float* __restrict__ out, long n) {
  const long i = ((long)blockIdx.x * 256 + threadIdx.x) * 4;
  if (i >= n) return;
  const ushort4 a = *reinterpret_cast<const ushort4*>(p + i);
  const ushort4 b = *reinterpret_cast<const ushort4*>(p + n + i);
  const float4 r = *reinterpret_cast<const float4*>(res + i);
  float4 o;
  o.x = bf2f(a.x) + bf2f(b.x) + r.x;
  o.y = bf2f(a.y) + bf2f(b.y) + r.y;
  o.z = bf2f(a.z) + bf2f(b.z) + r.z;
  o.w = bf2f(a.w) + bf2f(b.w) + r.w;
  if (BIAS) {
    const int col = (int)(i & 2047);
    const float4 bv = *reinterpret_cast<const float4*>(bias + col);
    o.x += bv.x; o.y += bv.y; o.z += bv.z; o.w += bv.w;
  }
  *reinterpret_cast<float4*>(out + i) = o;
}

// ---------------------------------------------------------------------------
// Causal flash attention, KVBLK=64 (serial q-tile pair, 80 VGPR — the
// measured-best version; R14's merged pair cost 140 VGPR -> occupancy
// 10.8% -> +55 us. Do not merge states without a VGPR budget).
// ---------------------------------------------------------------------------
__global__ __launch_bounds__(256) void flash_attn(
    const unsigned short* __restrict__ Q, const unsigned short* __restrict__ KV,
    const unsigned short* __restrict__ Vt, unsigned short* __restrict__ O) {
  constexpr int S = 2048;
  const int tid = threadIdx.x, lane = tid & 63, w = tid >> 6;
  const int g = lane >> 4, lcol = lane & 15;
  const int wg = blockIdx.x;              // 0..511
  const int x8 = wg & 7, q64 = wg >> 3;   // q64 0..63
  const int p = q64 & 15, hi = q64 >> 4;
  const int bh = x8 * 4 + hi;             // 0..31
  const int b = bh >> 4, h = bh & 15;
  const long kvrow0 = (long)b * S;
  const int hd0 = h * 128;

  __shared__ __align__(16) unsigned short Kl[64 * 128];   // [k][d] swizzled
  __shared__ __align__(16) unsigned short Vl[128 * 64];   // [d][k] swizzled
  __shared__ __align__(16) unsigned short Pl[4 * 16 * 72];

  const float kscale = 0.08838834764831845f * 1.4426950408889634f; // /sqrt(128)*log2e

  for (int ti = 0; ti < 2; ti++) {
    const int t = ti ? (31 - p) : p;
    const int qbase = t * 64;
    bf16x8 qf[4];
#pragma unroll
    for (int dc = 0; dc < 4; dc++)
      qf[dc] = *reinterpret_cast<const bf16x8*>(
          Q + (kvrow0 + qbase + w * 16 + lcol) * 2048 + hd0 + dc * 32 + g * 8);
    f32x4 oacc[8] = {};
    float mst[4] = {NEG_INF, NEG_INF, NEG_INF, NEG_INF};
    float lst[4] = {0.f, 0.f, 0.f, 0.f};
    const int nk = t + 1;
    for (int kt = 0; kt < nk; kt++) {
      const int kv0 = kt * 64;
      __syncthreads();
#pragma unroll
      for (int i = 0; i < 4; i++) {
        const int o16 = i * 256 + tid;
        const int kr = o16 >> 4, ks = o16 & 15;
        GLDS16(KV + (kvrow0 + kv0 + kr) * 4096 + hd0 + 8 * (ks ^ (kr & 7)),
               Kl + o16 * 8);
        const int vd = o16 >> 3, vs = o16 & 7;
        GLDS16(Vt + ((long)bh * 128 + vd) * 2048 + kv0 + 8 * (vs ^ (vd & 7)),
               Vl + o16 * 8);
      }
      __syncthreads();
      // QK^T: 16q x 64k
      f32x4 sc[4] = {};
      __builtin_amdgcn_s_setprio(1);
#pragma unroll
      for (int dc = 0; dc < 4; dc++) {
#pragma unroll
        for (int c = 0; c < 4; c++) {
          const bf16x8 kf = *reinterpret_cast<const bf16x8*>(
              Kl + (c * 16 + lcol) * 128 + 8 * ((4 * dc + g) ^ (lcol & 7)));
          sc[c] = __builtin_amdgcn_mfma_f32_16x16x32_bf16(qf[dc], kf, sc[c], 0, 0, 0);
        }
      }
      __builtin_amdgcn_s_setprio(0);
      float s[4][4];
      const int qrow = qbase + w * 16 + g * 4;
      if (kt == nk - 1) {
#pragma unroll
        for (int c = 0; c < 4; c++) {
          const int col = kv0 + c * 16 + lcol;
#pragma unroll
          for (int r = 0; r < 4; r++)
            s[c][r] = (col <= qrow + r) ? sc[c][r] * kscale : NEG_INF;
        }
      } else {
#pragma unroll
        for (int c = 0; c < 4; c++)
#pragma unroll
          for (int r = 0; r < 4; r++) s[c][r] = sc[c][r] * kscale;
      }
      float pm[4];
#pragma unroll
      for (int r = 0; r < 4; r++) {
        float mx = fmaxf(fmaxf(s[0][r], s[1][r]), fmaxf(s[2][r], s[3][r]));
        mx = fmaxf(mx, __shfl_xor(mx, 1));
        mx = fmaxf(mx, __shfl_xor(mx, 2));
        mx = fmaxf(mx, __shfl_xor(mx, 4));
        mx = fmaxf(mx, __shfl_xor(mx, 8));
        pm[r] = mx;
      }
      bool need = false;
#pragma unroll
      for (int r = 0; r < 4; r++) need = need || (pm[r] > mst[r] + 11.5f);
      if (__any(need)) {
#pragma unroll
        for (int r = 0; r < 4; r++) {
          const float mnew = fmaxf(mst[r], pm[r]);
          const float corr = exp2f(mst[r] - mnew);
          mst[r] = mnew;
          lst[r] *= corr;
#pragma unroll
          for (int db = 0; db < 8; db++) oacc[db][r] *= corr;
        }
      }
#pragma unroll
      for (int r = 0; r < 4; r++) {
        float ps = 0.f;
#pragma unroll
        for (int c = 0; c < 4; c++) {
          const float pv = exp2f(s[c][r] - mst[r]);
          Pl[(w * 16 + g * 4 + r) * 72 + c * 16 + lcol] = f2bf(pv);
          ps += pv;
        }
        ps += __shfl_xor(ps, 1); ps += __shfl_xor(ps, 2);
        ps += __shfl_xor(ps, 4); ps += __shfl_xor(ps, 8);
        lst[r] += ps;
      }
      __builtin_amdgcn_s_setprio(1);
#pragma unroll
      for (int kk = 0; kk < 2; kk++) {
        const bf16x8 pf = *reinterpret_cast<const bf16x8*>(
            Pl + (w * 16 + lcol) * 72 + kk * 32 + g * 8);
#pragma unroll
        for (int db = 0; db < 8; db++) {
          const bf16x8 vf = *reinterpret_cast<const bf16x8*>(
              Vl + (db * 16 + lcol) * 64 + 8 * ((4 * kk + g) ^ (lcol & 7)));
          oacc[db] = __builtin_amdgcn_mfma_f32_16x16x32_bf16(pf, vf, oacc[db], 0, 0, 0);
        }
      }
      __builtin_amdgcn_s_setprio(0);
    }
#pragma unroll
    for (int db = 0; db < 8; db++)
#pragma unroll
      for (int r = 0; r < 4; r++) {
        const int qi = qbase + w * 16 + g * 4 + r;
        O[(kvrow0 + qi) * 2048 + hd0 + db * 16 + lcol] = f2bf(oacc[db][r] / lst[r]);
      }
  }
}

// ---------------------------------------------------------------------------
// launch
// ---------------------------------------------------------------------------
extern "C" void kernel_launch(void* const* d_in, const int* in_sizes, int n_in,
                              void* d_out, int out_size, void* d_ws, size_t ws_size,
                              hipStream_t stream) {
  (void)in_sizes; (void)n_in; (void)out_size; (void)ws_size;
  const float* x     = (const float*)d_in[0];
  const float* W_dq  = (const float*)d_in[1];
  const float* W_uq  = (const float*)d_in[2];
  const float* qlng  = (const float*)d_in[3];
  const float* qlnb  = (const float*)d_in[4];
  const float* W_dkv = (const float*)d_in[5];
  const float* W_ukv = (const float*)d_in[6];
  const float* klng  = (const float*)d_in[7];
  const float* klnb  = (const float*)d_in[8];
  const float* W_o   = (const float*)d_in[9];
  const float* n1g   = (const float*)d_in[10];
  const float* n1b   = (const float*)d_in[11];
  const float* n2g   = (const float*)d_in[12];
  const float* n2b   = (const float*)d_in[13];
  const float* fc1w  = (const float*)d_in[14];
  const float* fc1b  = (const float*)d_in[15];
  const float* fc2w  = (const float*)d_in[16];
  const float* fc2b  = (const float*)d_in[17];
  float* out = (float*)d_out;

  char* ws = (char*)d_ws;
  // region A [0,32M): normed -> Obuf -> fc2bb
  unsigned short* normed = (unsigned short*)(ws + 0);
  unsigned short* Obuf   = (unsigned short*)(ws + 0);
  unsigned short* fc2bb  = (unsigned short*)(ws + 0);
  // region B [32M,64M): cqkv_part (4x8MB bf16) -> KV -> fc1bb -> fc2part
  unsigned short* cqkv_part = (unsigned short*)(ws + 33554432);
  unsigned short* KV        = (unsigned short*)(ws + 33554432);
  unsigned short* fc1bb     = (unsigned short*)(ws + 33554432);
  unsigned short* fc2part   = (unsigned short*)(ws + 33554432);
  // region C [64M,68M): cq
  unsigned short* cq  = (unsigned short*)(ws + 67108864);
  // region D [68M,84.7M): Qb -> h1
  unsigned short* Qb = (unsigned short*)(ws + 71303168);
  unsigned short* h1 = (unsigned short*)(ws + 71303168);
  // region E [84M,117.6M): ckv (early) -> x2 (late)
  unsigned short* ckv = (unsigned short*)(ws + 88080384);
  float* x2           = (float*)(ws + 88080384);
  // region F [116M,180M): Vt -> wopart -> hmid
  unsigned short* Vtb    = (unsigned short*)(ws + 121634816);
  unsigned short* wopart = (unsigned short*)(ws + 121634816);
  unsigned short* hmid   = (unsigned short*)(ws + 121634816);
  // region G [180M,...): transposed/cast weights
  unsigned short* dqkv_t = (unsigned short*)(ws + 188743680);  // 1024 x 2048
  unsigned short* uq_t   = dqkv_t + 2097152;                   // 2048 x 512
  unsigned short* ukv_t  = uq_t + 1048576;                     // 4096 x 512
  unsigned short* wo_b   = ukv_t + 2097152;                    // 2048 x 2048

  const dim3 blk(256);
  const dim3 blk8(512);

  // all weight transposes + W_o cast in one launch
  weight_prep<<<9216, blk, 0, stream>>>(W_dq, W_dkv, W_uq, W_ukv, W_o,
                                        dqkv_t, uq_t, ukv_t, wo_b);

  // LN1
  layernorm_bf16<2048><<<4096, blk, 0, stream>>>(x, n1g, n1b, normed, 2048);
  // cqkv partials = normed @ [W_dq | W_dkv]  (split-K=4, bf16 partials)
  gemm256p<false, false, true, false, false><<<dim3(16, 4, 4), blk8, 0, stream>>>(
      normed, dqkv_t, nullptr, cqkv_part, nullptr, nullptr, nullptr, nullptr,
      4096, 1024, 2048, 2048, 512, 512);
  // cq / ckv = LN over summed partials (one launch, no combine pass)
  ln2x512<<<4096, blk, 0, stream>>>(cqkv_part, qlng, qlnb, klng, klnb, cq, ckv);
  // KV = ckv @ W_ukv (V half -> Vt transposed)  AND  Q = cq @ W_uq,
  // one launch: by<16 -> KV, by>=16 -> Q-up (384 blocks)
  gemm256p<false, false, true, true, true><<<dim3(16, 24), blk8, 0, stream>>>(
      ckv, ukv_t, nullptr, KV, Vtb, cq, uq_t, Qb,
      4096, 4096, 512, 512, 512, 0);
  // attention (serial q-tile pairs, 80-VGPR version)
  flash_attn<<<dim3(512), blk, 0, stream>>>(Qb, KV, Vtb, Obuf);
  // W_o partials: split-K=2 (Vt dead -> region F)
  gemm256p<false, false, true, false, false><<<dim3(16, 8, 2), blk8, 0, stream>>>(
      Obuf, wo_b, nullptr, wopart, nullptr, nullptr, nullptr, nullptr,
      4096, 2048, 2048, 2048, 1024, 1024);
  // fc1 + fc2 weight casts (regions B and A both free now), one launch
  cast2_f32_bf16<<<32768, blk, 0, stream>>>(fc1w, fc1bb, 16777216L, fc2w, fc2bb);
  // x2 = x + p0 + p1 ; h1 = LN(x2)   (fused)
  combine_ln<<<4096, blk, 0, stream>>>(wopart, x, n2g, n2b, x2, h1, 8388608L);
  // h_mid = relu(h1 @ fc1^T + b1)
  gemm256p<true, true, true, false, false><<<dim3(16, 32), blk8, 0, stream>>>(
      h1, fc1bb, fc1b, hmid, nullptr, nullptr, nullptr, nullptr,
      4096, 8192, 2048, 2048, 2048, 0);
  // fc2 partials: split-K=2
  gemm256p<false, false, true, false, false><<<dim3(16, 8, 2), blk8, 0, stream>>>(
      hmid, fc2bb, nullptr, fc2part, nullptr, nullptr, nullptr, nullptr,
      4096, 2048, 8192, 8192, 4096, 4096);
  // out = p0 + p1 + b2 + x2
  combine2<true><<<8192, blk, 0, stream>>>(fc2part, fc2b, x2, out, 8388608L);
}